// Round 12
// baseline (276.085 us; speedup 1.0000x reference)
//
#include <hip/hip_runtime.h>
#include <hip/hip_fp16.h>

#define LRELU(v) ((v) > 0.f ? (v) : 0.2f * (v))
#define LOG2E 1.44269504088896340736f

typedef _Float16 f16x8 __attribute__((ext_vector_type(8)));
typedef _Float16 f16x4 __attribute__((ext_vector_type(4)));
typedef _Float16 f16x2 __attribute__((ext_vector_type(2)));
typedef float f32x4 __attribute__((ext_vector_type(4)));

__device__ __forceinline__ float fexp2(float x) {
    return __builtin_amdgcn_exp2f(x);
}

__device__ __forceinline__ f16x8 f16x8_zero() {
    f16x8 v;
#pragma unroll
    for (int j = 0; j < 8; ++j) v[j] = (_Float16)0.f;
    return v;
}

// ---------------- CSR construction ----------------
__global__ __launch_bounds__(256) void hist_kernel(const int* __restrict__ dst,
                                                   int* __restrict__ cnt, int E) {
    int e = blockIdx.x * 256 + threadIdx.x;
    if (e < E) atomicAdd(&cnt[dst[e]], 1);
}

__global__ __launch_bounds__(256) void scan_blk(const int* __restrict__ cnt,
                                                int* __restrict__ offv,
                                                int* __restrict__ bsum, int N) {
    __shared__ int sh[256];
    const int t = threadIdx.x;
    const int base = blockIdx.x * 1024 + t * 4;
    int v0 = (base + 0 < N) ? cnt[base + 0] : 0;
    int v1 = (base + 1 < N) ? cnt[base + 1] : 0;
    int v2 = (base + 2 < N) ? cnt[base + 2] : 0;
    int v3 = (base + 3 < N) ? cnt[base + 3] : 0;
    const int T = v0 + v1 + v2 + v3;
    sh[t] = T;
    __syncthreads();
    for (int o = 1; o < 256; o <<= 1) {
        int x = (t >= o) ? sh[t - o] : 0;
        __syncthreads();
        sh[t] += x;
        __syncthreads();
    }
    const int excl = sh[t] - T;
    if (t == 255) bsum[blockIdx.x] = sh[255];
    if (base + 0 < N) offv[base + 0] = excl;
    if (base + 1 < N) offv[base + 1] = excl + v0;
    if (base + 2 < N) offv[base + 2] = excl + v0 + v1;
    if (base + 3 < N) offv[base + 3] = excl + v0 + v1 + v2;
}

__global__ __launch_bounds__(64) void scan_top(int* __restrict__ bsum,
                                               int* __restrict__ offv,
                                               int NB, int N) {
    const int t = threadIdx.x;
    const int v = (t < NB) ? bsum[t] : 0;
    int incl = v;
#pragma unroll
    for (int o = 1; o < 64; o <<= 1) {
        int x = __shfl_up(incl, o);
        if (t >= o) incl += x;
    }
    if (t < NB) bsum[t] = incl - v;
    if (t == NB - 1) offv[N] = incl;
}

__global__ __launch_bounds__(256) void scan_add(int* __restrict__ offv,
                                                const int* __restrict__ bsum, int N) {
    const int base = blockIdx.x * 1024 + threadIdx.x * 4;
    const int add = bsum[blockIdx.x];
#pragma unroll
    for (int i = 0; i < 4; ++i)
        if (base + i < N) offv[base + i] += add;
}

__global__ __launch_bounds__(256) void fill_kernel(const int* __restrict__ dst,
                                                   const int* __restrict__ srcv,
                                                   const int* __restrict__ offv,
                                                   int* __restrict__ cur,
                                                   int* __restrict__ csrsrc, int E) {
    int e = blockIdx.x * 256 + threadIdx.x;
    if (e < E) {
        int d = dst[e];
        int p = atomicAdd(&cur[d], 1);
        csrsrc[offv[d] + p] = srcv[e];
    }
}

// ---------------- weight prep: all three transposes in one dispatch ----------
__global__ __launch_bounds__(256) void prep_w_all(
    const float* __restrict__ W1, const float* __restrict__ W2,
    const float* __restrict__ W3, _Float16* __restrict__ Wt1,
    _Float16* __restrict__ Wt2, _Float16* __restrict__ Wt3) {
    const int S1 = 128 * 256, S2 = 256 * 256, S3 = 256 * 64;
    int idx = blockIdx.x * 256 + threadIdx.x;
    if (idx < S1) {
        int k = idx >> 8, nn = idx & 255;
        Wt1[nn * 128 + k] = (_Float16)W1[idx];
    } else if (idx < S1 + S2) {
        int i = idx - S1;
        int k = i >> 8, nn = i & 255;
        Wt2[nn * 256 + k] = (_Float16)W2[i];
    } else if (idx < S1 + S2 + S3) {
        int i = idx - S1 - S2;
        int k = i >> 6, nn = i & 63;
        Wt3[nn * 256 + k] = (_Float16)W3[i];
    }
}

// ---------------- gemm64: BM=64, 4 waves (col-split), KC=64 double-buffered ----
// 782 blocks -> 3.05 blocks/CU (balanced). Prefetch next K-chunk into regs AFTER
// the barrier so global loads overlap MFMA. Fused alpha (log2-domain), f16 out.
// N fixed = 256 (H=4, head = wave).
template <int K, bool AF32>
__global__ __launch_bounds__(256) void gemm64_fused(
    const void* __restrict__ Av, const _Float16* __restrict__ Wt,
    const float* __restrict__ a_s, const float* __restrict__ a_d,
    _Float16* __restrict__ hout, float* __restrict__ als,
    float* __restrict__ ald, int M) {
    constexpr int NKC = K / 64;
    __shared__ f16x8 Atile[2][512];   // [buf][row*8 + swizzled cc], 8 KB each
    const _Float16* A16 = (const _Float16*)Av;
    const float* A32 = (const float*)Av;
    const int t = threadIdx.x;
    const int lane = t & 63;
    const int wn = t >> 6;            // wave = 64-col block = head
    const int m0 = blockIdx.x * 64;
    const int l15 = lane & 15, lg = lane >> 4;

    // staging assignment: thread t owns chunks t and t+256 (chunk = 16B = 8 f16)
    const int r0 = t >> 3, c0 = t & 7;
    const int r1 = (t + 256) >> 3, c1 = t & 7;   // (t+256)&7 == t&7
    const int gr0 = min(m0 + r0, M - 1);
    const int gr1 = min(m0 + r1, M - 1);

    f16x8 s0, s1;
    auto FETCH = [&](int kc) {
        if constexpr (AF32) {
            float4 p = *(const float4*)(A32 + (size_t)gr0 * K + kc + c0 * 8);
            float4 q = *(const float4*)(A32 + (size_t)gr0 * K + kc + c0 * 8 + 4);
            s0[0] = (_Float16)p.x; s0[1] = (_Float16)p.y;
            s0[2] = (_Float16)p.z; s0[3] = (_Float16)p.w;
            s0[4] = (_Float16)q.x; s0[5] = (_Float16)q.y;
            s0[6] = (_Float16)q.z; s0[7] = (_Float16)q.w;
            float4 r = *(const float4*)(A32 + (size_t)gr1 * K + kc + c1 * 8);
            float4 u = *(const float4*)(A32 + (size_t)gr1 * K + kc + c1 * 8 + 4);
            s1[0] = (_Float16)r.x; s1[1] = (_Float16)r.y;
            s1[2] = (_Float16)r.z; s1[3] = (_Float16)r.w;
            s1[4] = (_Float16)u.x; s1[5] = (_Float16)u.y;
            s1[6] = (_Float16)u.z; s1[7] = (_Float16)u.w;
        } else {
            s0 = *(const f16x8*)(A16 + (size_t)gr0 * K + kc + c0 * 8);
            s1 = *(const f16x8*)(A16 + (size_t)gr1 * K + kc + c1 * 8);
        }
    };
    FETCH(0);

    f32x4 acc[4][4];
    const f32x4 zz = {0.f, 0.f, 0.f, 0.f};
#pragma unroll
    for (int mi = 0; mi < 4; ++mi)
#pragma unroll
        for (int ni = 0; ni < 4; ++ni) acc[mi][ni] = zz;

    int cur = 0;
#pragma unroll
    for (int kci = 0; kci < NKC; ++kci) {
        Atile[cur][r0 * 8 + (c0 ^ (r0 & 7))] = s0;   // waits on prefetch
        Atile[cur][r1 * 8 + (c1 ^ (r1 & 7))] = s1;
        __syncthreads();                              // drain, then issue next
        if (kci + 1 < NKC) FETCH((kci + 1) * 64);     // overlaps MFMA below
#pragma unroll
        for (int ks = 0; ks < 2; ++ks) {
            f16x8 af[4], bf[4];
#pragma unroll
            for (int mi = 0; mi < 4; ++mi) {
                const int row = mi * 16 + l15;
                af[mi] = Atile[cur][row * 8 + ((ks * 4 + lg) ^ (row & 7))];
            }
#pragma unroll
            for (int ni = 0; ni < 4; ++ni) {
                const int col = wn * 64 + ni * 16 + l15;
                bf[ni] = *(const f16x8*)(Wt + (size_t)col * K + kci * 64 + ks * 32 + lg * 8);
            }
#pragma unroll
            for (int mi = 0; mi < 4; ++mi)
#pragma unroll
                for (int ni = 0; ni < 4; ++ni)
                    acc[mi][ni] = __builtin_amdgcn_mfma_f32_16x16x32_f16(
                        af[mi], bf[ni], acc[mi][ni], 0, 0, 0);
        }
        cur ^= 1;
    }
    // epilogue: C/D col=lane&15, row=(lane>>4)*4+j; alpha pre-scaled by log2(e)
    const int head = wn;
    float a4s[4], a4d[4];
#pragma unroll
    for (int ni = 0; ni < 4; ++ni) {
        a4s[ni] = a_s[head * 64 + ni * 16 + l15] * LOG2E;
        a4d[ni] = a_d[head * 64 + ni * 16 + l15] * LOG2E;
    }
#pragma unroll
    for (int mi = 0; mi < 4; ++mi)
#pragma unroll
        for (int j = 0; j < 4; ++j) {
            const int r = m0 + mi * 16 + lg * 4 + j;
            if (r < M) {
                float s1v = 0.f, s2v = 0.f;
#pragma unroll
                for (int ni = 0; ni < 4; ++ni) {
                    const float v = acc[mi][ni][j];
                    s1v += v * a4s[ni];
                    s2v += v * a4d[ni];
                    hout[(size_t)r * 256 + wn * 64 + ni * 16 + l15] = (_Float16)v;
                }
#pragma unroll
                for (int o = 8; o; o >>= 1) {
                    s1v += __shfl_xor(s1v, o);
                    s2v += __shfl_xor(s2v, o);
                }
                if (l15 == 0) {
                    als[(size_t)r * 4 + head] = s1v;
                    ald[(size_t)r * 4 + head] = s2v;
                }
            }
        }
}

// ---------------- layer-3 GEMM (old structure, N=64) ----------------
template <int WM, int WN, int K, int H, bool AF32>
__global__ __launch_bounds__(WM * WN * 64) void gemm_f16_fused(
    const void* __restrict__ Av, const _Float16* __restrict__ Wt,
    const float* __restrict__ a_s, const float* __restrict__ a_d,
    _Float16* __restrict__ hout, float* __restrict__ als,
    float* __restrict__ ald, int M, int Nn) {
    constexpr int BM = WM * 64;
    constexpr int T = WM * WN * 64;
    constexpr int CHUNKS = BM * 16;
    __shared__ f16x8 Atile[BM * 16];
    const _Float16* A16 = (const _Float16*)Av;
    const float* A32 = (const float*)Av;
    const int t = threadIdx.x;
    const int lane = t & 63;
    const int wv = t >> 6;
    const int wm = wv / WN, wn = wv % WN;
    const int m0 = blockIdx.x * BM;
    const int n0 = blockIdx.y * (WN * 64);
    const int l15 = lane & 15, lg = lane >> 4;

    f32x4 acc[4][4];
    const f32x4 zz = {0.f, 0.f, 0.f, 0.f};
#pragma unroll
    for (int mi = 0; mi < 4; ++mi)
#pragma unroll
        for (int ni = 0; ni < 4; ++ni) acc[mi][ni] = zz;

    for (int kc = 0; kc < K; kc += 128) {
        __syncthreads();
#pragma unroll
        for (int i = 0; i < CHUNKS / T; ++i) {
            const int c = i * T + t;
            const int row = c >> 4, cc = c & 15;
            const int gr = m0 + row;
            f16x8 v;
            if (gr < M) {
                if constexpr (AF32) {
                    float4 p = *(const float4*)(A32 + (size_t)gr * K + kc + cc * 8);
                    float4 q = *(const float4*)(A32 + (size_t)gr * K + kc + cc * 8 + 4);
                    v[0] = (_Float16)p.x; v[1] = (_Float16)p.y;
                    v[2] = (_Float16)p.z; v[3] = (_Float16)p.w;
                    v[4] = (_Float16)q.x; v[5] = (_Float16)q.y;
                    v[6] = (_Float16)q.z; v[7] = (_Float16)q.w;
                } else {
                    v = *(const f16x8*)(A16 + (size_t)gr * K + kc + cc * 8);
                }
            } else {
                v = f16x8_zero();
            }
            Atile[(row * 16 + cc) ^ (row & 7)] = v;
        }
        __syncthreads();
#pragma unroll
        for (int ks = 0; ks < 4; ++ks) {
            f16x8 af[4], bf[4];
#pragma unroll
            for (int mi = 0; mi < 4; ++mi) {
                const int row = wm * 64 + mi * 16 + l15;
                af[mi] = Atile[(row * 16 + ks * 4 + lg) ^ (row & 7)];
            }
#pragma unroll
            for (int ni = 0; ni < 4; ++ni) {
                const int col = n0 + wn * 64 + ni * 16 + l15;
                bf[ni] = *(const f16x8*)(Wt + (size_t)col * K + kc + ks * 32 + lg * 8);
            }
#pragma unroll
            for (int mi = 0; mi < 4; ++mi)
#pragma unroll
                for (int ni = 0; ni < 4; ++ni)
                    acc[mi][ni] = __builtin_amdgcn_mfma_f32_16x16x32_f16(
                        af[mi], bf[ni], acc[mi][ni], 0, 0, 0);
        }
    }
    const int head = (n0 + wn * 64) >> 6;
    float a4s[4], a4d[4];
#pragma unroll
    for (int ni = 0; ni < 4; ++ni) {
        a4s[ni] = a_s[head * 64 + ni * 16 + l15] * LOG2E;
        a4d[ni] = a_d[head * 64 + ni * 16 + l15] * LOG2E;
    }
#pragma unroll
    for (int mi = 0; mi < 4; ++mi)
#pragma unroll
        for (int j = 0; j < 4; ++j) {
            const int r = m0 + wm * 64 + mi * 16 + lg * 4 + j;
            if (r < M) {
                float s1 = 0.f, s2 = 0.f;
#pragma unroll
                for (int ni = 0; ni < 4; ++ni) {
                    const float v = acc[mi][ni][j];
                    s1 += v * a4s[ni];
                    s2 += v * a4d[ni];
                    hout[(size_t)r * Nn + n0 + wn * 64 + ni * 16 + l15] = (_Float16)v;
                }
#pragma unroll
                for (int o = 8; o; o >>= 1) {
                    s1 += __shfl_xor(s1, o);
                    s2 += __shfl_xor(s2, o);
                }
                if (l15 == 0) {
                    als[(size_t)r * H + head] = s1;
                    ald[(size_t)r * H + head] = s2;
                }
            }
        }
}

// ---------------- aggregation H=4: 2 nodes per wave (unchanged, at plateau) ---
__global__ __launch_bounds__(256) void gat_agg_h4(
    const _Float16* __restrict__ hhf, const float4* __restrict__ als4,
    const float4* __restrict__ ald4, const int* __restrict__ csrsrc,
    const int* __restrict__ offv, const float* __restrict__ bias,
    _Float16* __restrict__ outh, int N) {
    __shared__ int sidAll[4][2][36];
    __shared__ float wTAll[4][2][4][36];
    const int wv = threadIdx.x >> 6;
    const int l = threadIdx.x & 63;
    const int half = l >> 5;
    const int q = l & 31;
    const int n = (blockIdx.x * 4 + wv) * 2 + half;
    if (n >= N) return;
    const int hh = q >> 3;
    int* sid = sidAll[wv][half];
    float* wrow = wTAll[wv][half][hh];
    float (*wT)[36] = wTAll[wv][half];
    const int start = offv[n];
    const int deg = offv[n + 1] - start;
    const float4 ad = ald4[n];
    const float4 asf = als4[n];
    float4 ws4;
    ws4.x = fexp2(LRELU(asf.x + ad.x));
    ws4.y = fexp2(LRELU(asf.y + ad.y));
    ws4.z = fexp2(LRELU(asf.z + ad.z));
    ws4.w = fexp2(LRELU(asf.w + ad.w));
    float wself = ws4.x;
    wself = (hh == 1) ? ws4.y : wself;
    wself = (hh == 2) ? ws4.z : wself;
    wself = (hh == 3) ? ws4.w : wself;
    float accA[8], accB[8] = {};
    {
        const f16x8 hv = *(const f16x8*)(hhf + (size_t)n * 256 + q * 8);
#pragma unroll
        for (int c = 0; c < 8; ++c) accA[c] = (float)hv[c] * wself;
    }
    float dsum = wself;

    for (int base = 0; base < deg; base += 32) {
        const int nb = min(32, deg - base);
        int s = 0;
        float4 w4 = {0.f, 0.f, 0.f, 0.f};
        if (q < nb) {
            s = csrsrc[start + base + q];
            const float4 av = als4[s];
            w4.x = fexp2(LRELU(av.x + ad.x));
            w4.y = fexp2(LRELU(av.y + ad.y));
            w4.z = fexp2(LRELU(av.z + ad.z));
            w4.w = fexp2(LRELU(av.w + ad.w));
        }
        sid[q] = s;
        wT[0][q] = w4.x;
        wT[1][q] = w4.y;
        wT[2][q] = w4.z;
        wT[3][q] = w4.w;
        __threadfence_block();
        int i = 0;
        for (; i + 1 < nb; i += 2) {
            const int sA = sid[i], sB = sid[i + 1];
            const float wA = wrow[i], wB = wrow[i + 1];
            const f16x8 hA = *(const f16x8*)(hhf + (size_t)sA * 256 + q * 8);
            const f16x8 hB = *(const f16x8*)(hhf + (size_t)sB * 256 + q * 8);
            dsum += wA + wB;
#pragma unroll
            for (int c = 0; c < 8; ++c) {
                accA[c] += (float)hA[c] * wA;
                accB[c] += (float)hB[c] * wB;
            }
        }
        if (i < nb) {
            const int sA = sid[i];
            const float wA = wrow[i];
            const f16x8 hA = *(const f16x8*)(hhf + (size_t)sA * 256 + q * 8);
            dsum += wA;
#pragma unroll
            for (int c = 0; c < 8; ++c) accA[c] += (float)hA[c] * wA;
        }
        __threadfence_block();
    }
    const float inv = 1.f / (dsum + 1e-16f);
    const float4 bv0 = *(const float4*)(bias + q * 8);
    const float4 bv1 = *(const float4*)(bias + q * 8 + 4);
    float o8[8];
#pragma unroll
    for (int c = 0; c < 8; ++c) o8[c] = (accA[c] + accB[c]) * inv;
    o8[0] += bv0.x; o8[1] += bv0.y; o8[2] += bv0.z; o8[3] += bv0.w;
    o8[4] += bv1.x; o8[5] += bv1.y; o8[6] += bv1.z; o8[7] += bv1.w;
#pragma unroll
    for (int c = 0; c < 8; ++c)
        o8[c] = (o8[c] > 0.f) ? o8[c] : (__expf(o8[c]) - 1.f);
    f16x8 st;
#pragma unroll
    for (int c = 0; c < 8; ++c) st[c] = (_Float16)o8[c];
    *(f16x8*)(outh + (size_t)n * 256 + q * 8) = st;
}

// ---------------- aggregation H=1: 2 nodes per wave, lean (no classifier) ----
__global__ __launch_bounds__(256) void gat_agg_h1(
    const _Float16* __restrict__ hhf, const float* __restrict__ als,
    const float* __restrict__ ald, const int* __restrict__ csrsrc,
    const int* __restrict__ offv, const float* __restrict__ bias,
    _Float16* __restrict__ outh, int N) {
    __shared__ int sidAll[4][2][36];
    __shared__ float wAll[4][2][36];
    const int wv = threadIdx.x >> 6;
    const int l = threadIdx.x & 63;
    const int half = l >> 5;
    const int q = l & 31;
    const int n = (blockIdx.x * 4 + wv) * 2 + half;
    if (n >= N) return;
    int* sid = sidAll[wv][half];
    float* wsh = wAll[wv][half];
    const int start = offv[n];
    const int deg = offv[n + 1] - start;
    const float ad = ald[n];
    const float wself = fexp2(LRELU(als[n] + ad));
    float acc0, acc1;
    {
        const f16x2 hv = *(const f16x2*)(hhf + (size_t)n * 64 + q * 2);
        acc0 = (float)hv[0] * wself;
        acc1 = (float)hv[1] * wself;
    }
    float dsum = wself;

    for (int base = 0; base < deg; base += 32) {
        const int nb = min(32, deg - base);
        int s = 0;
        float w = 0.f;
        if (q < nb) {
            s = csrsrc[start + base + q];
            w = fexp2(LRELU(als[s] + ad));
        }
        sid[q] = s;
        wsh[q] = w;
        __threadfence_block();
        for (int i = 0; i < nb; ++i) {
            const int si = sid[i];
            const float wi = wsh[i];
            const f16x2 hv = *(const f16x2*)(hhf + (size_t)si * 64 + q * 2);
            dsum += wi;
            acc0 += (float)hv[0] * wi;
            acc1 += (float)hv[1] * wi;
        }
        __threadfence_block();
    }
    const float inv = 1.f / (dsum + 1e-16f);
    const float v0 = fmaxf(acc0 * inv + bias[q * 2], 0.f);
    const float v1 = fmaxf(acc1 * inv + bias[q * 2 + 1], 0.f);
    f16x2 st;
    st[0] = (_Float16)v0;
    st[1] = (_Float16)v1;
    *(f16x2*)(outh + (size_t)n * 64 + q * 2) = st;
}

// ---------------- classifier: 1 thread per node, x[64] in regs ----------------
__global__ __launch_bounds__(256) void classifier_ls(
    const _Float16* __restrict__ h3, const float* __restrict__ cW1,
    const float* __restrict__ cb1, const float* __restrict__ cW2,
    const float* __restrict__ cb2, float* __restrict__ outp, int N) {
    __shared__ float w1s[2048];   // cW1 [64][32]
    __shared__ float w2s[64];     // cW2 [32][2]
    __shared__ float b1s[32];
    for (int i = threadIdx.x; i < 2048; i += 256) w1s[i] = cW1[i];
    if (threadIdx.x < 64) w2s[threadIdx.x] = cW2[threadIdx.x];
    if (threadIdx.x < 32) b1s[threadIdx.x] = cb1[threadIdx.x];
    __syncthreads();
    const int n = blockIdx.x * 256 + threadIdx.x;
    if (n >= N) return;
    float x[64];
#pragma unroll
    for (int i = 0; i < 8; ++i) {
        const f16x8 v = *(const f16x8*)(h3 + (size_t)n * 64 + i * 8);
#pragma unroll
        for (int j = 0; j < 8; ++j) x[i * 8 + j] = (float)v[j];
    }
    float l0 = cb2[0], l1 = cb2[1];
    for (int j = 0; j < 32; ++j) {
        float s = b1s[j];
#pragma unroll
        for (int c = 0; c < 64; ++c) s += x[c] * w1s[c * 32 + j];
        s = fmaxf(s, 0.f);
        l0 += s * w2s[j * 2];
        l1 += s * w2s[j * 2 + 1];
    }
    const float mm = fmaxf(l0, l1);
    const float lse = mm + logf(__expf(l0 - mm) + __expf(l1 - mm));
    outp[(size_t)n * 2 + 0] = l0 - lse;
    outp[(size_t)n * 2 + 1] = l1 - lse;
}

extern "C" void kernel_launch(void* const* d_in, const int* in_sizes, int n_in,
                              void* d_out, int out_size, void* d_ws, size_t ws_size,
                              hipStream_t stream) {
    const float* x   = (const float*)d_in[0];
    const int*   ei  = (const int*)d_in[1];
    const float* W1  = (const float*)d_in[2];
    const float* a1s = (const float*)d_in[3];
    const float* a1d = (const float*)d_in[4];
    const float* b1  = (const float*)d_in[5];
    const float* W2  = (const float*)d_in[6];
    const float* a2s = (const float*)d_in[7];
    const float* a2d = (const float*)d_in[8];
    const float* b2  = (const float*)d_in[9];
    const float* W3  = (const float*)d_in[10];
    const float* a3s = (const float*)d_in[11];
    const float* a3d = (const float*)d_in[12];
    const float* b3  = (const float*)d_in[13];
    const float* cW1 = (const float*)d_in[14];
    const float* cb1 = (const float*)d_in[15];
    const float* cW2 = (const float*)d_in[16];
    const float* cb2 = (const float*)d_in[17];

    const int N = in_sizes[0] / 128;   // 50000
    const int E = in_sizes[1] / 2;     // 500000
    const int* srcv = ei;
    const int* dstv = ei + E;

    // workspace layout, all segments 16B-aligned
    char* p = (char*)d_ws;
    _Float16* slotA = (_Float16*)p; p += (size_t)N * 256 * 2;   // h1h / h2h / h3h
    _Float16* slotB = (_Float16*)p; p += (size_t)N * 256 * 2;   // a1h / a2h / agg3 out
    float* als = (float*)p; p += (size_t)N * 4 * 4;
    float* ald = (float*)p; p += (size_t)N * 4 * 4;
    int* cnt = (int*)p; p += (size_t)N * 4;
    int* offv = (int*)p; p += (size_t)(N + 4) * 4;
    int* csr = (int*)p; p += (size_t)E * 4;
    _Float16* Wt1 = (_Float16*)p; p += (size_t)128 * 256 * 2;
    _Float16* Wt2 = (_Float16*)p; p += (size_t)256 * 256 * 2;
    _Float16* Wt3 = (_Float16*)p; p += (size_t)256 * 64 * 2;
    int* bsum = (int*)p;

    // weight transposes (one dispatch)
    prep_w_all<<<(128 * 256 + 256 * 256 + 256 * 64 + 255) / 256, 256, 0, stream>>>(
        W1, W2, W3, Wt1, Wt2, Wt3);

    // CSR by destination
    const int NB = (N + 1023) / 1024;   // 49
    hipMemsetAsync(cnt, 0, (size_t)N * sizeof(int), stream);
    hist_kernel<<<(E + 255) / 256, 256, 0, stream>>>(dstv, cnt, E);
    scan_blk<<<NB, 256, 0, stream>>>(cnt, offv, bsum, N);
    scan_top<<<1, 64, 0, stream>>>(bsum, offv, NB, N);
    scan_add<<<NB, 256, 0, stream>>>(offv, bsum, N);
    hipMemsetAsync(cnt, 0, (size_t)N * sizeof(int), stream);
    fill_kernel<<<(E + 255) / 256, 256, 0, stream>>>(dstv, srcv, offv, cnt, csr, E);

    const int MB64 = (N + 63) / 64;      // 782
    const int MB256 = (N + 255) / 256;   // 196
    const int AGG8 = (N + 7) / 8;        // 6250
    const int CLS = (N + 255) / 256;     // 196

    // ---- layer 1 (128 -> 256, H=4, ELU); A = x fp32, converted in staging ----
    gemm64_fused<128, true><<<MB64, 256, 0, stream>>>(
        x, Wt1, a1s, a1d, slotA, als, ald, N);
    gat_agg_h4<<<AGG8, 256, 0, stream>>>(slotA, (const float4*)als,
                                         (const float4*)ald, csr, offv, b1,
                                         slotB, N);

    // ---- layer 2 (256 -> 256, H=4, ELU) ----
    gemm64_fused<256, false><<<MB64, 256, 0, stream>>>(
        slotB, Wt2, a2s, a2d, slotA, als, ald, N);
    gat_agg_h4<<<AGG8, 256, 0, stream>>>(slotA, (const float4*)als,
                                         (const float4*)ald, csr, offv, b2,
                                         slotB, N);

    // ---- layer 3 (256 -> 64, H=1) ----
    gemm_f16_fused<4, 1, 256, 1, false><<<dim3(MB256, 1), 256, 0, stream>>>(
        slotB, Wt3, a3s, a3d, slotA, als, ald, N, 64);
    gat_agg_h1<<<AGG8, 256, 0, stream>>>(slotA, als, ald, csr, offv, b3,
                                         slotB, N);

    // ---- classifier + log_softmax ----
    classifier_ls<<<CLS, 256, 0, stream>>>(slotB, cW1, cb1, cW2, cb2,
                                           (float*)d_out, N);
}

// Round 13
// 274.585 us; speedup vs baseline: 1.0055x; 1.0055x over previous
//
#include <hip/hip_runtime.h>
#include <hip/hip_fp16.h>

#define LRELU(v) ((v) > 0.f ? (v) : 0.2f * (v))
#define LOG2E 1.44269504088896340736f

typedef _Float16 f16x8 __attribute__((ext_vector_type(8)));
typedef _Float16 f16x2 __attribute__((ext_vector_type(2)));
typedef float f32x4 __attribute__((ext_vector_type(4)));

__device__ __forceinline__ float fexp2(float x) {
    return __builtin_amdgcn_exp2f(x);
}

// ---------------- CSR construction ----------------
__global__ __launch_bounds__(256) void hist_kernel(const int* __restrict__ dst,
                                                   int* __restrict__ cnt, int E) {
    int e = blockIdx.x * 256 + threadIdx.x;
    if (e < E) atomicAdd(&cnt[dst[e]], 1);
}

__global__ __launch_bounds__(256) void scan_blk(const int* __restrict__ cnt,
                                                int* __restrict__ offv,
                                                int* __restrict__ bsum, int N) {
    __shared__ int sh[256];
    const int t = threadIdx.x;
    const int base = blockIdx.x * 1024 + t * 4;
    int v0 = (base + 0 < N) ? cnt[base + 0] : 0;
    int v1 = (base + 1 < N) ? cnt[base + 1] : 0;
    int v2 = (base + 2 < N) ? cnt[base + 2] : 0;
    int v3 = (base + 3 < N) ? cnt[base + 3] : 0;
    const int T = v0 + v1 + v2 + v3;
    sh[t] = T;
    __syncthreads();
    for (int o = 1; o < 256; o <<= 1) {
        int x = (t >= o) ? sh[t - o] : 0;
        __syncthreads();
        sh[t] += x;
        __syncthreads();
    }
    const int excl = sh[t] - T;
    if (t == 255) bsum[blockIdx.x] = sh[255];
    if (base + 0 < N) offv[base + 0] = excl;
    if (base + 1 < N) offv[base + 1] = excl + v0;
    if (base + 2 < N) offv[base + 2] = excl + v0 + v1;
    if (base + 3 < N) offv[base + 3] = excl + v0 + v1 + v2;
}

__global__ __launch_bounds__(64) void scan_top(int* __restrict__ bsum,
                                               int* __restrict__ offv,
                                               int NB, int N) {
    const int t = threadIdx.x;
    const int v = (t < NB) ? bsum[t] : 0;
    int incl = v;
#pragma unroll
    for (int o = 1; o < 64; o <<= 1) {
        int x = __shfl_up(incl, o);
        if (t >= o) incl += x;
    }
    if (t < NB) bsum[t] = incl - v;
    if (t == NB - 1) offv[N] = incl;
}

__global__ __launch_bounds__(256) void scan_add(int* __restrict__ offv,
                                                const int* __restrict__ bsum, int N) {
    const int base = blockIdx.x * 1024 + threadIdx.x * 4;
    const int add = bsum[blockIdx.x];
#pragma unroll
    for (int i = 0; i < 4; ++i)
        if (base + i < N) offv[base + i] += add;
}

// fill consumes cnt via atomicSub (no zeroed cursor needed)
__global__ __launch_bounds__(256) void fill_kernel(const int* __restrict__ dst,
                                                   const int* __restrict__ srcv,
                                                   const int* __restrict__ offv,
                                                   int* __restrict__ cnt,
                                                   int* __restrict__ csrsrc, int E) {
    int e = blockIdx.x * 256 + threadIdx.x;
    if (e < E) {
        int d = dst[e];
        int p = atomicSub(&cnt[d], 1);   // p in [1..count]
        csrsrc[offv[d] + p - 1] = srcv[e];
    }
}

// ---------------- weight prep: all three transposes in one dispatch ----------
__global__ __launch_bounds__(256) void prep_w_all(
    const float* __restrict__ W1, const float* __restrict__ W2,
    const float* __restrict__ W3, _Float16* __restrict__ Wt1,
    _Float16* __restrict__ Wt2, _Float16* __restrict__ Wt3) {
    const int S1 = 128 * 256, S2 = 256 * 256, S3 = 256 * 64;
    int idx = blockIdx.x * 256 + threadIdx.x;
    if (idx < S1) {
        int k = idx >> 8, nn = idx & 255;
        Wt1[nn * 128 + k] = (_Float16)W1[idx];
    } else if (idx < S1 + S2) {
        int i = idx - S1;
        int k = i >> 8, nn = i & 255;
        Wt2[nn * 256 + k] = (_Float16)W2[i];
    } else if (idx < S1 + S2 + S3) {
        int i = idx - S1 - S2;
        int k = i >> 6, nn = i & 63;
        Wt3[nn * 256 + k] = (_Float16)W3[i];
    }
}

// ---------------- gemm64: BM=64, N=256, 4 waves (col-split), KC=64 dbuf ------
template <int K, bool AF32>
__global__ __launch_bounds__(256) void gemm64_fused(
    const void* __restrict__ Av, const _Float16* __restrict__ Wt,
    const float* __restrict__ a_s, const float* __restrict__ a_d,
    _Float16* __restrict__ hout, float* __restrict__ als,
    float* __restrict__ ald, int M) {
    constexpr int NKC = K / 64;
    __shared__ f16x8 Atile[2][512];
    const _Float16* A16 = (const _Float16*)Av;
    const float* A32 = (const float*)Av;
    const int t = threadIdx.x;
    const int lane = t & 63;
    const int wn = t >> 6;
    const int m0 = blockIdx.x * 64;
    const int l15 = lane & 15, lg = lane >> 4;

    const int r0 = t >> 3, c0 = t & 7;
    const int r1 = (t + 256) >> 3, c1 = t & 7;
    const int gr0 = min(m0 + r0, M - 1);
    const int gr1 = min(m0 + r1, M - 1);

    f16x8 s0, s1;
    auto FETCH = [&](int kc) {
        if constexpr (AF32) {
            float4 p = *(const float4*)(A32 + (size_t)gr0 * K + kc + c0 * 8);
            float4 q = *(const float4*)(A32 + (size_t)gr0 * K + kc + c0 * 8 + 4);
            s0[0] = (_Float16)p.x; s0[1] = (_Float16)p.y;
            s0[2] = (_Float16)p.z; s0[3] = (_Float16)p.w;
            s0[4] = (_Float16)q.x; s0[5] = (_Float16)q.y;
            s0[6] = (_Float16)q.z; s0[7] = (_Float16)q.w;
            float4 r = *(const float4*)(A32 + (size_t)gr1 * K + kc + c1 * 8);
            float4 u = *(const float4*)(A32 + (size_t)gr1 * K + kc + c1 * 8 + 4);
            s1[0] = (_Float16)r.x; s1[1] = (_Float16)r.y;
            s1[2] = (_Float16)r.z; s1[3] = (_Float16)r.w;
            s1[4] = (_Float16)u.x; s1[5] = (_Float16)u.y;
            s1[6] = (_Float16)u.z; s1[7] = (_Float16)u.w;
        } else {
            s0 = *(const f16x8*)(A16 + (size_t)gr0 * K + kc + c0 * 8);
            s1 = *(const f16x8*)(A16 + (size_t)gr1 * K + kc + c1 * 8);
        }
    };
    FETCH(0);

    f32x4 acc[4][4];
    const f32x4 zz = {0.f, 0.f, 0.f, 0.f};
#pragma unroll
    for (int mi = 0; mi < 4; ++mi)
#pragma unroll
        for (int ni = 0; ni < 4; ++ni) acc[mi][ni] = zz;

    int cur = 0;
#pragma unroll
    for (int kci = 0; kci < NKC; ++kci) {
        Atile[cur][r0 * 8 + (c0 ^ (r0 & 7))] = s0;
        Atile[cur][r1 * 8 + (c1 ^ (r1 & 7))] = s1;
        __syncthreads();
        if (kci + 1 < NKC) FETCH((kci + 1) * 64);
#pragma unroll
        for (int ks = 0; ks < 2; ++ks) {
            f16x8 af[4], bf[4];
#pragma unroll
            for (int mi = 0; mi < 4; ++mi) {
                const int row = mi * 16 + l15;
                af[mi] = Atile[cur][row * 8 + ((ks * 4 + lg) ^ (row & 7))];
            }
#pragma unroll
            for (int ni = 0; ni < 4; ++ni) {
                const int col = wn * 64 + ni * 16 + l15;
                bf[ni] = *(const f16x8*)(Wt + (size_t)col * K + kci * 64 + ks * 32 + lg * 8);
            }
#pragma unroll
            for (int mi = 0; mi < 4; ++mi)
#pragma unroll
                for (int ni = 0; ni < 4; ++ni)
                    acc[mi][ni] = __builtin_amdgcn_mfma_f32_16x16x32_f16(
                        af[mi], bf[ni], acc[mi][ni], 0, 0, 0);
        }
        cur ^= 1;
    }
    const int head = wn;
    float a4s[4], a4d[4];
#pragma unroll
    for (int ni = 0; ni < 4; ++ni) {
        a4s[ni] = a_s[head * 64 + ni * 16 + l15] * LOG2E;
        a4d[ni] = a_d[head * 64 + ni * 16 + l15] * LOG2E;
    }
#pragma unroll
    for (int mi = 0; mi < 4; ++mi)
#pragma unroll
        for (int j = 0; j < 4; ++j) {
            const int r = m0 + mi * 16 + lg * 4 + j;
            if (r < M) {
                float s1v = 0.f, s2v = 0.f;
#pragma unroll
                for (int ni = 0; ni < 4; ++ni) {
                    const float v = acc[mi][ni][j];
                    s1v += v * a4s[ni];
                    s2v += v * a4d[ni];
                    hout[(size_t)r * 256 + wn * 64 + ni * 16 + l15] = (_Float16)v;
                }
#pragma unroll
                for (int o = 8; o; o >>= 1) {
                    s1v += __shfl_xor(s1v, o);
                    s2v += __shfl_xor(s2v, o);
                }
                if (l15 == 0) {
                    als[(size_t)r * 4 + head] = s1v;
                    ald[(size_t)r * 4 + head] = s2v;
                }
            }
        }
}

// ---------------- gemm64n64: BM=64, N=64, 4 waves (row-split), KC=64 dbuf ----
// Layer 3: wave wv owns rows wv*16..wv*16+15, all 64 cols. 782 blocks.
template <int K>
__global__ __launch_bounds__(256) void gemm64n64_fused(
    const _Float16* __restrict__ A16, const _Float16* __restrict__ Wt,
    const float* __restrict__ a_s, const float* __restrict__ a_d,
    _Float16* __restrict__ hout, float* __restrict__ als,
    float* __restrict__ ald, int M) {
    constexpr int NKC = K / 64;
    __shared__ f16x8 Atile[2][512];
    const int t = threadIdx.x;
    const int lane = t & 63;
    const int wv = t >> 6;              // wave = 16-row block
    const int m0 = blockIdx.x * 64;
    const int l15 = lane & 15, lg = lane >> 4;

    const int r0 = t >> 3, c0 = t & 7;
    const int r1 = (t + 256) >> 3, c1 = t & 7;
    const int gr0 = min(m0 + r0, M - 1);
    const int gr1 = min(m0 + r1, M - 1);

    f16x8 s0, s1;
    auto FETCH = [&](int kc) {
        s0 = *(const f16x8*)(A16 + (size_t)gr0 * K + kc + c0 * 8);
        s1 = *(const f16x8*)(A16 + (size_t)gr1 * K + kc + c1 * 8);
    };
    FETCH(0);

    f32x4 acc[4];
    const f32x4 zz = {0.f, 0.f, 0.f, 0.f};
#pragma unroll
    for (int ni = 0; ni < 4; ++ni) acc[ni] = zz;

    int cur = 0;
#pragma unroll
    for (int kci = 0; kci < NKC; ++kci) {
        Atile[cur][r0 * 8 + (c0 ^ (r0 & 7))] = s0;
        Atile[cur][r1 * 8 + (c1 ^ (r1 & 7))] = s1;
        __syncthreads();
        if (kci + 1 < NKC) FETCH((kci + 1) * 64);
#pragma unroll
        for (int ks = 0; ks < 2; ++ks) {
            const int row = wv * 16 + l15;
            const f16x8 af = Atile[cur][row * 8 + ((ks * 4 + lg) ^ (row & 7))];
            f16x8 bf[4];
#pragma unroll
            for (int ni = 0; ni < 4; ++ni) {
                const int col = ni * 16 + l15;
                bf[ni] = *(const f16x8*)(Wt + (size_t)col * K + kci * 64 + ks * 32 + lg * 8);
            }
#pragma unroll
            for (int ni = 0; ni < 4; ++ni)
                acc[ni] = __builtin_amdgcn_mfma_f32_16x16x32_f16(
                    af, bf[ni], acc[ni], 0, 0, 0);
        }
        cur ^= 1;
    }
    // epilogue: H=1 alpha over all 64 cols; C/D col=l15, row = wv*16 + lg*4 + j
    float a4s[4], a4d[4];
#pragma unroll
    for (int ni = 0; ni < 4; ++ni) {
        a4s[ni] = a_s[ni * 16 + l15] * LOG2E;
        a4d[ni] = a_d[ni * 16 + l15] * LOG2E;
    }
#pragma unroll
    for (int j = 0; j < 4; ++j) {
        const int r = m0 + wv * 16 + lg * 4 + j;
        if (r < M) {
            float s1v = 0.f, s2v = 0.f;
#pragma unroll
            for (int ni = 0; ni < 4; ++ni) {
                const float v = acc[ni][j];
                s1v += v * a4s[ni];
                s2v += v * a4d[ni];
                hout[(size_t)r * 64 + ni * 16 + l15] = (_Float16)v;
            }
#pragma unroll
            for (int o = 8; o; o >>= 1) {
                s1v += __shfl_xor(s1v, o);
                s2v += __shfl_xor(s2v, o);
            }
            if (l15 == 0) {
                als[r] = s1v;
                ald[r] = s2v;
            }
        }
    }
}

// ---------------- aggregation H=4: 2 nodes per wave (at gather plateau) -------
__global__ __launch_bounds__(256) void gat_agg_h4(
    const _Float16* __restrict__ hhf, const float4* __restrict__ als4,
    const float4* __restrict__ ald4, const int* __restrict__ csrsrc,
    const int* __restrict__ offv, const float* __restrict__ bias,
    _Float16* __restrict__ outh, int N) {
    __shared__ int sidAll[4][2][36];
    __shared__ float wTAll[4][2][4][36];
    const int wv = threadIdx.x >> 6;
    const int l = threadIdx.x & 63;
    const int half = l >> 5;
    const int q = l & 31;
    const int n = (blockIdx.x * 4 + wv) * 2 + half;
    if (n >= N) return;
    const int hh = q >> 3;
    int* sid = sidAll[wv][half];
    float* wrow = wTAll[wv][half][hh];
    float (*wT)[36] = wTAll[wv][half];
    const int start = offv[n];
    const int deg = offv[n + 1] - start;
    const float4 ad = ald4[n];
    const float4 asf = als4[n];
    float4 ws4;
    ws4.x = fexp2(LRELU(asf.x + ad.x));
    ws4.y = fexp2(LRELU(asf.y + ad.y));
    ws4.z = fexp2(LRELU(asf.z + ad.z));
    ws4.w = fexp2(LRELU(asf.w + ad.w));
    float wself = ws4.x;
    wself = (hh == 1) ? ws4.y : wself;
    wself = (hh == 2) ? ws4.z : wself;
    wself = (hh == 3) ? ws4.w : wself;
    float accA[8], accB[8] = {};
    {
        const f16x8 hv = *(const f16x8*)(hhf + (size_t)n * 256 + q * 8);
#pragma unroll
        for (int c = 0; c < 8; ++c) accA[c] = (float)hv[c] * wself;
    }
    float dsum = wself;

    for (int base = 0; base < deg; base += 32) {
        const int nb = min(32, deg - base);
        int s = 0;
        float4 w4 = {0.f, 0.f, 0.f, 0.f};
        if (q < nb) {
            s = csrsrc[start + base + q];
            const float4 av = als4[s];
            w4.x = fexp2(LRELU(av.x + ad.x));
            w4.y = fexp2(LRELU(av.y + ad.y));
            w4.z = fexp2(LRELU(av.z + ad.z));
            w4.w = fexp2(LRELU(av.w + ad.w));
        }
        sid[q] = s;
        wT[0][q] = w4.x;
        wT[1][q] = w4.y;
        wT[2][q] = w4.z;
        wT[3][q] = w4.w;
        __threadfence_block();
        int i = 0;
        for (; i + 1 < nb; i += 2) {
            const int sA = sid[i], sB = sid[i + 1];
            const float wA = wrow[i], wB = wrow[i + 1];
            const f16x8 hA = *(const f16x8*)(hhf + (size_t)sA * 256 + q * 8);
            const f16x8 hB = *(const f16x8*)(hhf + (size_t)sB * 256 + q * 8);
            dsum += wA + wB;
#pragma unroll
            for (int c = 0; c < 8; ++c) {
                accA[c] += (float)hA[c] * wA;
                accB[c] += (float)hB[c] * wB;
            }
        }
        if (i < nb) {
            const int sA = sid[i];
            const float wA = wrow[i];
            const f16x8 hA = *(const f16x8*)(hhf + (size_t)sA * 256 + q * 8);
            dsum += wA;
#pragma unroll
            for (int c = 0; c < 8; ++c) accA[c] += (float)hA[c] * wA;
        }
        __threadfence_block();
    }
    const float inv = 1.f / (dsum + 1e-16f);
    const float4 bv0 = *(const float4*)(bias + q * 8);
    const float4 bv1 = *(const float4*)(bias + q * 8 + 4);
    float o8[8];
#pragma unroll
    for (int c = 0; c < 8; ++c) o8[c] = (accA[c] + accB[c]) * inv;
    o8[0] += bv0.x; o8[1] += bv0.y; o8[2] += bv0.z; o8[3] += bv0.w;
    o8[4] += bv1.x; o8[5] += bv1.y; o8[6] += bv1.z; o8[7] += bv1.w;
#pragma unroll
    for (int c = 0; c < 8; ++c)
        o8[c] = (o8[c] > 0.f) ? o8[c] : (__expf(o8[c]) - 1.f);
    f16x8 st;
#pragma unroll
    for (int c = 0; c < 8; ++c) st[c] = (_Float16)o8[c];
    *(f16x8*)(outh + (size_t)n * 256 + q * 8) = st;
}

// ---------------- aggregation H=1: 2 nodes per wave ----------
__global__ __launch_bounds__(256) void gat_agg_h1(
    const _Float16* __restrict__ hhf, const float* __restrict__ als,
    const float* __restrict__ ald, const int* __restrict__ csrsrc,
    const int* __restrict__ offv, const float* __restrict__ bias,
    _Float16* __restrict__ outh, int N) {
    __shared__ int sidAll[4][2][36];
    __shared__ float wAll[4][2][36];
    const int wv = threadIdx.x >> 6;
    const int l = threadIdx.x & 63;
    const int half = l >> 5;
    const int q = l & 31;
    const int n = (blockIdx.x * 4 + wv) * 2 + half;
    if (n >= N) return;
    int* sid = sidAll[wv][half];
    float* wsh = wAll[wv][half];
    const int start = offv[n];
    const int deg = offv[n + 1] - start;
    const float ad = ald[n];
    const float wself = fexp2(LRELU(als[n] + ad));
    float acc0, acc1;
    {
        const f16x2 hv = *(const f16x2*)(hhf + (size_t)n * 64 + q * 2);
        acc0 = (float)hv[0] * wself;
        acc1 = (float)hv[1] * wself;
    }
    float dsum = wself;

    for (int base = 0; base < deg; base += 32) {
        const int nb = min(32, deg - base);
        int s = 0;
        float w = 0.f;
        if (q < nb) {
            s = csrsrc[start + base + q];
            w = fexp2(LRELU(als[s] + ad));
        }
        sid[q] = s;
        wsh[q] = w;
        __threadfence_block();
        for (int i = 0; i < nb; ++i) {
            const int si = sid[i];
            const float wi = wsh[i];
            const f16x2 hv = *(const f16x2*)(hhf + (size_t)si * 64 + q * 2);
            dsum += wi;
            acc0 += (float)hv[0] * wi;
            acc1 += (float)hv[1] * wi;
        }
        __threadfence_block();
    }
    const float inv = 1.f / (dsum + 1e-16f);
    const float v0 = fmaxf(acc0 * inv + bias[q * 2], 0.f);
    const float v1 = fmaxf(acc1 * inv + bias[q * 2 + 1], 0.f);
    f16x2 st;
    st[0] = (_Float16)v0;
    st[1] = (_Float16)v1;
    *(f16x2*)(outh + (size_t)n * 64 + q * 2) = st;
}

// ---------------- classifier: 1 thread per node, x[64] in regs ----------------
__global__ __launch_bounds__(256) void classifier_ls(
    const _Float16* __restrict__ h3, const float* __restrict__ cW1,
    const float* __restrict__ cb1, const float* __restrict__ cW2,
    const float* __restrict__ cb2, float* __restrict__ outp, int N) {
    __shared__ float w1s[2048];
    __shared__ float w2s[64];
    __shared__ float b1s[32];
    for (int i = threadIdx.x; i < 2048; i += 256) w1s[i] = cW1[i];
    if (threadIdx.x < 64) w2s[threadIdx.x] = cW2[threadIdx.x];
    if (threadIdx.x < 32) b1s[threadIdx.x] = cb1[threadIdx.x];
    __syncthreads();
    const int n = blockIdx.x * 256 + threadIdx.x;
    if (n >= N) return;
    float x[64];
#pragma unroll
    for (int i = 0; i < 8; ++i) {
        const f16x8 v = *(const f16x8*)(h3 + (size_t)n * 64 + i * 8);
#pragma unroll
        for (int j = 0; j < 8; ++j) x[i * 8 + j] = (float)v[j];
    }
    float l0 = cb2[0], l1 = cb2[1];
    for (int j = 0; j < 32; ++j) {
        float s = b1s[j];
#pragma unroll
        for (int c = 0; c < 64; ++c) s += x[c] * w1s[c * 32 + j];
        s = fmaxf(s, 0.f);
        l0 += s * w2s[j * 2];
        l1 += s * w2s[j * 2 + 1];
    }
    const float mm = fmaxf(l0, l1);
    const float lse = mm + logf(__expf(l0 - mm) + __expf(l1 - mm));
    outp[(size_t)n * 2 + 0] = l0 - lse;
    outp[(size_t)n * 2 + 1] = l1 - lse;
}

extern "C" void kernel_launch(void* const* d_in, const int* in_sizes, int n_in,
                              void* d_out, int out_size, void* d_ws, size_t ws_size,
                              hipStream_t stream) {
    const float* x   = (const float*)d_in[0];
    const int*   ei  = (const int*)d_in[1];
    const float* W1  = (const float*)d_in[2];
    const float* a1s = (const float*)d_in[3];
    const float* a1d = (const float*)d_in[4];
    const float* b1  = (const float*)d_in[5];
    const float* W2  = (const float*)d_in[6];
    const float* a2s = (const float*)d_in[7];
    const float* a2d = (const float*)d_in[8];
    const float* b2  = (const float*)d_in[9];
    const float* W3  = (const float*)d_in[10];
    const float* a3s = (const float*)d_in[11];
    const float* a3d = (const float*)d_in[12];
    const float* b3  = (const float*)d_in[13];
    const float* cW1 = (const float*)d_in[14];
    const float* cb1 = (const float*)d_in[15];
    const float* cW2 = (const float*)d_in[16];
    const float* cb2 = (const float*)d_in[17];

    const int N = in_sizes[0] / 128;   // 50000
    const int E = in_sizes[1] / 2;     // 500000
    const int* srcv = ei;
    const int* dstv = ei + E;

    // workspace layout, all segments 16B-aligned
    char* p = (char*)d_ws;
    _Float16* slotA = (_Float16*)p; p += (size_t)N * 256 * 2;   // h1h / h2h / h3h
    _Float16* slotB = (_Float16*)p; p += (size_t)N * 256 * 2;   // a1h / a2h / agg3 out
    float* als = (float*)p; p += (size_t)N * 4 * 4;
    float* ald = (float*)p; p += (size_t)N * 4 * 4;
    int* cnt = (int*)p; p += (size_t)N * 4;
    int* offv = (int*)p; p += (size_t)(N + 4) * 4;
    int* csr = (int*)p; p += (size_t)E * 4;
    _Float16* Wt1 = (_Float16*)p; p += (size_t)128 * 256 * 2;
    _Float16* Wt2 = (_Float16*)p; p += (size_t)256 * 256 * 2;
    _Float16* Wt3 = (_Float16*)p; p += (size_t)256 * 64 * 2;
    int* bsum = (int*)p;

    // weight transposes (one dispatch)
    prep_w_all<<<(128 * 256 + 256 * 256 + 256 * 64 + 255) / 256, 256, 0, stream>>>(
        W1, W2, W3, Wt1, Wt2, Wt3);

    // CSR by destination (fill consumes cnt — one memset only)
    const int NB = (N + 1023) / 1024;   // 49
    hipMemsetAsync(cnt, 0, (size_t)N * sizeof(int), stream);
    hist_kernel<<<(E + 255) / 256, 256, 0, stream>>>(dstv, cnt, E);
    scan_blk<<<NB, 256, 0, stream>>>(cnt, offv, bsum, N);
    scan_top<<<1, 64, 0, stream>>>(bsum, offv, NB, N);
    scan_add<<<NB, 256, 0, stream>>>(offv, bsum, N);
    fill_kernel<<<(E + 255) / 256, 256, 0, stream>>>(dstv, srcv, offv, cnt, csr, E);

    const int MB64 = (N + 63) / 64;      // 782
    const int AGG8 = (N + 7) / 8;        // 6250
    const int CLS = (N + 255) / 256;     // 196

    // ---- layer 1 (128 -> 256, H=4, ELU); A = x fp32, converted in staging ----
    gemm64_fused<128, true><<<MB64, 256, 0, stream>>>(
        x, Wt1, a1s, a1d, slotA, als, ald, N);
    gat_agg_h4<<<AGG8, 256, 0, stream>>>(slotA, (const float4*)als,
                                         (const float4*)ald, csr, offv, b1,
                                         slotB, N);

    // ---- layer 2 (256 -> 256, H=4, ELU) ----
    gemm64_fused<256, false><<<MB64, 256, 0, stream>>>(
        slotB, Wt2, a2s, a2d, slotA, als, ald, N);
    gat_agg_h4<<<AGG8, 256, 0, stream>>>(slotA, (const float4*)als,
                                         (const float4*)ald, csr, offv, b2,
                                         slotB, N);

    // ---- layer 3 (256 -> 64, H=1) ----
    gemm64n64_fused<256><<<MB64, 256, 0, stream>>>(
        slotB, Wt3, a3s, a3d, slotA, als, ald, N);
    gat_agg_h1<<<AGG8, 256, 0, stream>>>(slotA, als, ald, csr, offv, b3,
                                         slotB, N);

    // ---- classifier + log_softmax ----
    classifier_ls<<<CLS, 256, 0, stream>>>(slotB, cW1, cb1, cW2, cb2,
                                           (float*)d_out, N);
}

// Round 14
// 257.674 us; speedup vs baseline: 1.0715x; 1.0656x over previous
//
#include <hip/hip_runtime.h>
#include <hip/hip_fp16.h>

#define LRELU(v) ((v) > 0.f ? (v) : 0.2f * (v))
#define LOG2E 1.44269504088896340736f

typedef _Float16 f16x8 __attribute__((ext_vector_type(8)));
typedef _Float16 f16x2 __attribute__((ext_vector_type(2)));
typedef float f32x4 __attribute__((ext_vector_type(4)));

__device__ __forceinline__ float fexp2(float x) {
    return __builtin_amdgcn_exp2f(x);
}

// ---------------- CSR construction ----------------
__global__ __launch_bounds__(256) void hist_kernel(const int* __restrict__ dst,
                                                   int* __restrict__ cnt, int E) {
    int e = blockIdx.x * 256 + threadIdx.x;
    if (e < E) atomicAdd(&cnt[dst[e]], 1);
}

__global__ __launch_bounds__(256) void scan_blk(const int* __restrict__ cnt,
                                                int* __restrict__ offv,
                                                int* __restrict__ bsum, int N) {
    __shared__ int sh[256];
    const int t = threadIdx.x;
    const int base = blockIdx.x * 1024 + t * 4;
    int v0 = (base + 0 < N) ? cnt[base + 0] : 0;
    int v1 = (base + 1 < N) ? cnt[base + 1] : 0;
    int v2 = (base + 2 < N) ? cnt[base + 2] : 0;
    int v3 = (base + 3 < N) ? cnt[base + 3] : 0;
    const int T = v0 + v1 + v2 + v3;
    sh[t] = T;
    __syncthreads();
    for (int o = 1; o < 256; o <<= 1) {
        int x = (t >= o) ? sh[t - o] : 0;
        __syncthreads();
        sh[t] += x;
        __syncthreads();
    }
    const int excl = sh[t] - T;
    if (t == 255) bsum[blockIdx.x] = sh[255];
    if (base + 0 < N) offv[base + 0] = excl;
    if (base + 1 < N) offv[base + 1] = excl + v0;
    if (base + 2 < N) offv[base + 2] = excl + v0 + v1;
    if (base + 3 < N) offv[base + 3] = excl + v0 + v1 + v2;
}

// scan_add with integrated top-level scan: block b's offset = sum(bsum[0..b-1]),
// computed by a 64-lane butterfly (NB <= 64). Block NB-1 also writes offv[N].
__global__ __launch_bounds__(256) void scan_add2(int* __restrict__ offv,
                                                 const int* __restrict__ bsum,
                                                 int NB, int N) {
    __shared__ int s_add;
    const int t = threadIdx.x;
    const int b = blockIdx.x;
    if (t < 64) {
        int v = (t < NB) ? bsum[t] : 0;
        int pre = (t < b) ? v : 0;          // exclusive prefix for this block
        int tot = v;
#pragma unroll
        for (int o = 32; o; o >>= 1) {
            pre += __shfl_xor(pre, o);
            tot += __shfl_xor(tot, o);
        }
        if (t == 0) {
            s_add = pre;
            if (b == NB - 1) offv[N] = tot;  // total == E
        }
    }
    __syncthreads();
    const int add = s_add;
    const int base = b * 1024 + t * 4;
#pragma unroll
    for (int i = 0; i < 4; ++i)
        if (base + i < N) offv[base + i] += add;
}

// fill consumes cnt via atomicSub (no zeroed cursor needed)
__global__ __launch_bounds__(256) void fill_kernel(const int* __restrict__ dst,
                                                   const int* __restrict__ srcv,
                                                   const int* __restrict__ offv,
                                                   int* __restrict__ cnt,
                                                   int* __restrict__ csrsrc, int E) {
    int e = blockIdx.x * 256 + threadIdx.x;
    if (e < E) {
        int d = dst[e];
        int p = atomicSub(&cnt[d], 1);   // p in [1..count]
        csrsrc[offv[d] + p - 1] = srcv[e];
    }
}

// ---------------- weight prep: all three transposes in one dispatch ----------
__global__ __launch_bounds__(256) void prep_w_all(
    const float* __restrict__ W1, const float* __restrict__ W2,
    const float* __restrict__ W3, _Float16* __restrict__ Wt1,
    _Float16* __restrict__ Wt2, _Float16* __restrict__ Wt3) {
    const int S1 = 128 * 256, S2 = 256 * 256, S3 = 256 * 64;
    int idx = blockIdx.x * 256 + threadIdx.x;
    if (idx < S1) {
        int k = idx >> 8, nn = idx & 255;
        Wt1[nn * 128 + k] = (_Float16)W1[idx];
    } else if (idx < S1 + S2) {
        int i = idx - S1;
        int k = i >> 8, nn = i & 255;
        Wt2[nn * 256 + k] = (_Float16)W2[i];
    } else if (idx < S1 + S2 + S3) {
        int i = idx - S1 - S2;
        int k = i >> 6, nn = i & 63;
        Wt3[nn * 256 + k] = (_Float16)W3[i];
    }
}

// ---------------- gemm64: BM=64, N=256, 4 waves (col-split), KC=64 dbuf ------
template <int K, bool AF32>
__global__ __launch_bounds__(256) void gemm64_fused(
    const void* __restrict__ Av, const _Float16* __restrict__ Wt,
    const float* __restrict__ a_s, const float* __restrict__ a_d,
    _Float16* __restrict__ hout, float* __restrict__ als,
    float* __restrict__ ald, int M) {
    constexpr int NKC = K / 64;
    __shared__ f16x8 Atile[2][512];
    const _Float16* A16 = (const _Float16*)Av;
    const float* A32 = (const float*)Av;
    const int t = threadIdx.x;
    const int lane = t & 63;
    const int wn = t >> 6;
    const int m0 = blockIdx.x * 64;
    const int l15 = lane & 15, lg = lane >> 4;

    const int r0 = t >> 3, c0 = t & 7;
    const int r1 = (t + 256) >> 3, c1 = t & 7;
    const int gr0 = min(m0 + r0, M - 1);
    const int gr1 = min(m0 + r1, M - 1);

    f16x8 s0, s1;
    auto FETCH = [&](int kc) {
        if constexpr (AF32) {
            float4 p = *(const float4*)(A32 + (size_t)gr0 * K + kc + c0 * 8);
            float4 q = *(const float4*)(A32 + (size_t)gr0 * K + kc + c0 * 8 + 4);
            s0[0] = (_Float16)p.x; s0[1] = (_Float16)p.y;
            s0[2] = (_Float16)p.z; s0[3] = (_Float16)p.w;
            s0[4] = (_Float16)q.x; s0[5] = (_Float16)q.y;
            s0[6] = (_Float16)q.z; s0[7] = (_Float16)q.w;
            float4 r = *(const float4*)(A32 + (size_t)gr1 * K + kc + c1 * 8);
            float4 u = *(const float4*)(A32 + (size_t)gr1 * K + kc + c1 * 8 + 4);
            s1[0] = (_Float16)r.x; s1[1] = (_Float16)r.y;
            s1[2] = (_Float16)r.z; s1[3] = (_Float16)r.w;
            s1[4] = (_Float16)u.x; s1[5] = (_Float16)u.y;
            s1[6] = (_Float16)u.z; s1[7] = (_Float16)u.w;
        } else {
            s0 = *(const f16x8*)(A16 + (size_t)gr0 * K + kc + c0 * 8);
            s1 = *(const f16x8*)(A16 + (size_t)gr1 * K + kc + c1 * 8);
        }
    };
    FETCH(0);

    f32x4 acc[4][4];
    const f32x4 zz = {0.f, 0.f, 0.f, 0.f};
#pragma unroll
    for (int mi = 0; mi < 4; ++mi)
#pragma unroll
        for (int ni = 0; ni < 4; ++ni) acc[mi][ni] = zz;

    int cur = 0;
#pragma unroll
    for (int kci = 0; kci < NKC; ++kci) {
        Atile[cur][r0 * 8 + (c0 ^ (r0 & 7))] = s0;
        Atile[cur][r1 * 8 + (c1 ^ (r1 & 7))] = s1;
        __syncthreads();
        if (kci + 1 < NKC) FETCH((kci + 1) * 64);
#pragma unroll
        for (int ks = 0; ks < 2; ++ks) {
            f16x8 af[4], bf[4];
#pragma unroll
            for (int mi = 0; mi < 4; ++mi) {
                const int row = mi * 16 + l15;
                af[mi] = Atile[cur][row * 8 + ((ks * 4 + lg) ^ (row & 7))];
            }
#pragma unroll
            for (int ni = 0; ni < 4; ++ni) {
                const int col = wn * 64 + ni * 16 + l15;
                bf[ni] = *(const f16x8*)(Wt + (size_t)col * K + kci * 64 + ks * 32 + lg * 8);
            }
#pragma unroll
            for (int mi = 0; mi < 4; ++mi)
#pragma unroll
                for (int ni = 0; ni < 4; ++ni)
                    acc[mi][ni] = __builtin_amdgcn_mfma_f32_16x16x32_f16(
                        af[mi], bf[ni], acc[mi][ni], 0, 0, 0);
        }
        cur ^= 1;
    }
    const int head = wn;
    float a4s[4], a4d[4];
#pragma unroll
    for (int ni = 0; ni < 4; ++ni) {
        a4s[ni] = a_s[head * 64 + ni * 16 + l15] * LOG2E;
        a4d[ni] = a_d[head * 64 + ni * 16 + l15] * LOG2E;
    }
#pragma unroll
    for (int mi = 0; mi < 4; ++mi)
#pragma unroll
        for (int j = 0; j < 4; ++j) {
            const int r = m0 + mi * 16 + lg * 4 + j;
            if (r < M) {
                float s1v = 0.f, s2v = 0.f;
#pragma unroll
                for (int ni = 0; ni < 4; ++ni) {
                    const float v = acc[mi][ni][j];
                    s1v += v * a4s[ni];
                    s2v += v * a4d[ni];
                    hout[(size_t)r * 256 + wn * 64 + ni * 16 + l15] = (_Float16)v;
                }
#pragma unroll
                for (int o = 8; o; o >>= 1) {
                    s1v += __shfl_xor(s1v, o);
                    s2v += __shfl_xor(s2v, o);
                }
                if (l15 == 0) {
                    als[(size_t)r * 4 + head] = s1v;
                    ald[(size_t)r * 4 + head] = s2v;
                }
            }
        }
}

// ---------------- gemm64n64: BM=64, N=64, 4 waves (row-split), KC=64 dbuf ----
template <int K>
__global__ __launch_bounds__(256) void gemm64n64_fused(
    const _Float16* __restrict__ A16, const _Float16* __restrict__ Wt,
    const float* __restrict__ a_s, const float* __restrict__ a_d,
    _Float16* __restrict__ hout, float* __restrict__ als,
    float* __restrict__ ald, int M) {
    constexpr int NKC = K / 64;
    __shared__ f16x8 Atile[2][512];
    const int t = threadIdx.x;
    const int lane = t & 63;
    const int wv = t >> 6;
    const int m0 = blockIdx.x * 64;
    const int l15 = lane & 15, lg = lane >> 4;

    const int r0 = t >> 3, c0 = t & 7;
    const int r1 = (t + 256) >> 3, c1 = t & 7;
    const int gr0 = min(m0 + r0, M - 1);
    const int gr1 = min(m0 + r1, M - 1);

    f16x8 s0, s1;
    auto FETCH = [&](int kc) {
        s0 = *(const f16x8*)(A16 + (size_t)gr0 * K + kc + c0 * 8);
        s1 = *(const f16x8*)(A16 + (size_t)gr1 * K + kc + c1 * 8);
    };
    FETCH(0);

    f32x4 acc[4];
    const f32x4 zz = {0.f, 0.f, 0.f, 0.f};
#pragma unroll
    for (int ni = 0; ni < 4; ++ni) acc[ni] = zz;

    int cur = 0;
#pragma unroll
    for (int kci = 0; kci < NKC; ++kci) {
        Atile[cur][r0 * 8 + (c0 ^ (r0 & 7))] = s0;
        Atile[cur][r1 * 8 + (c1 ^ (r1 & 7))] = s1;
        __syncthreads();
        if (kci + 1 < NKC) FETCH((kci + 1) * 64);
#pragma unroll
        for (int ks = 0; ks < 2; ++ks) {
            const int row = wv * 16 + l15;
            const f16x8 af = Atile[cur][row * 8 + ((ks * 4 + lg) ^ (row & 7))];
            f16x8 bf[4];
#pragma unroll
            for (int ni = 0; ni < 4; ++ni) {
                const int col = ni * 16 + l15;
                bf[ni] = *(const f16x8*)(Wt + (size_t)col * K + kci * 64 + ks * 32 + lg * 8);
            }
#pragma unroll
            for (int ni = 0; ni < 4; ++ni)
                acc[ni] = __builtin_amdgcn_mfma_f32_16x16x32_f16(
                    af, bf[ni], acc[ni], 0, 0, 0);
        }
        cur ^= 1;
    }
    float a4s[4], a4d[4];
#pragma unroll
    for (int ni = 0; ni < 4; ++ni) {
        a4s[ni] = a_s[ni * 16 + l15] * LOG2E;
        a4d[ni] = a_d[ni * 16 + l15] * LOG2E;
    }
#pragma unroll
    for (int j = 0; j < 4; ++j) {
        const int r = m0 + wv * 16 + lg * 4 + j;
        if (r < M) {
            float s1v = 0.f, s2v = 0.f;
#pragma unroll
            for (int ni = 0; ni < 4; ++ni) {
                const float v = acc[ni][j];
                s1v += v * a4s[ni];
                s2v += v * a4d[ni];
                hout[(size_t)r * 64 + ni * 16 + l15] = (_Float16)v;
            }
#pragma unroll
            for (int o = 8; o; o >>= 1) {
                s1v += __shfl_xor(s1v, o);
                s2v += __shfl_xor(s2v, o);
            }
            if (l15 == 0) {
                als[r] = s1v;
                ald[r] = s2v;
            }
        }
    }
}

// ---------------- aggregation H=4: 2 nodes per wave (at gather plateau) -------
__global__ __launch_bounds__(256) void gat_agg_h4(
    const _Float16* __restrict__ hhf, const float4* __restrict__ als4,
    const float4* __restrict__ ald4, const int* __restrict__ csrsrc,
    const int* __restrict__ offv, const float* __restrict__ bias,
    _Float16* __restrict__ outh, int N) {
    __shared__ int sidAll[4][2][36];
    __shared__ float wTAll[4][2][4][36];
    const int wv = threadIdx.x >> 6;
    const int l = threadIdx.x & 63;
    const int half = l >> 5;
    const int q = l & 31;
    const int n = (blockIdx.x * 4 + wv) * 2 + half;
    if (n >= N) return;
    const int hh = q >> 3;
    int* sid = sidAll[wv][half];
    float* wrow = wTAll[wv][half][hh];
    float (*wT)[36] = wTAll[wv][half];
    const int start = offv[n];
    const int deg = offv[n + 1] - start;
    const float4 ad = ald4[n];
    const float4 asf = als4[n];
    float4 ws4;
    ws4.x = fexp2(LRELU(asf.x + ad.x));
    ws4.y = fexp2(LRELU(asf.y + ad.y));
    ws4.z = fexp2(LRELU(asf.z + ad.z));
    ws4.w = fexp2(LRELU(asf.w + ad.w));
    float wself = ws4.x;
    wself = (hh == 1) ? ws4.y : wself;
    wself = (hh == 2) ? ws4.z : wself;
    wself = (hh == 3) ? ws4.w : wself;
    float accA[8], accB[8] = {};
    {
        const f16x8 hv = *(const f16x8*)(hhf + (size_t)n * 256 + q * 8);
#pragma unroll
        for (int c = 0; c < 8; ++c) accA[c] = (float)hv[c] * wself;
    }
    float dsum = wself;

    for (int base = 0; base < deg; base += 32) {
        const int nb = min(32, deg - base);
        int s = 0;
        float4 w4 = {0.f, 0.f, 0.f, 0.f};
        if (q < nb) {
            s = csrsrc[start + base + q];
            const float4 av = als4[s];
            w4.x = fexp2(LRELU(av.x + ad.x));
            w4.y = fexp2(LRELU(av.y + ad.y));
            w4.z = fexp2(LRELU(av.z + ad.z));
            w4.w = fexp2(LRELU(av.w + ad.w));
        }
        sid[q] = s;
        wT[0][q] = w4.x;
        wT[1][q] = w4.y;
        wT[2][q] = w4.z;
        wT[3][q] = w4.w;
        __threadfence_block();
        int i = 0;
        for (; i + 1 < nb; i += 2) {
            const int sA = sid[i], sB = sid[i + 1];
            const float wA = wrow[i], wB = wrow[i + 1];
            const f16x8 hA = *(const f16x8*)(hhf + (size_t)sA * 256 + q * 8);
            const f16x8 hB = *(const f16x8*)(hhf + (size_t)sB * 256 + q * 8);
            dsum += wA + wB;
#pragma unroll
            for (int c = 0; c < 8; ++c) {
                accA[c] += (float)hA[c] * wA;
                accB[c] += (float)hB[c] * wB;
            }
        }
        if (i < nb) {
            const int sA = sid[i];
            const float wA = wrow[i];
            const f16x8 hA = *(const f16x8*)(hhf + (size_t)sA * 256 + q * 8);
            dsum += wA;
#pragma unroll
            for (int c = 0; c < 8; ++c) accA[c] += (float)hA[c] * wA;
        }
        __threadfence_block();
    }
    const float inv = 1.f / (dsum + 1e-16f);
    const float4 bv0 = *(const float4*)(bias + q * 8);
    const float4 bv1 = *(const float4*)(bias + q * 8 + 4);
    float o8[8];
#pragma unroll
    for (int c = 0; c < 8; ++c) o8[c] = (accA[c] + accB[c]) * inv;
    o8[0] += bv0.x; o8[1] += bv0.y; o8[2] += bv0.z; o8[3] += bv0.w;
    o8[4] += bv1.x; o8[5] += bv1.y; o8[6] += bv1.z; o8[7] += bv1.w;
#pragma unroll
    for (int c = 0; c < 8; ++c)
        o8[c] = (o8[c] > 0.f) ? o8[c] : (__expf(o8[c]) - 1.f);
    f16x8 st;
#pragma unroll
    for (int c = 0; c < 8; ++c) st[c] = (_Float16)o8[c];
    *(f16x8*)(outh + (size_t)n * 256 + q * 8) = st;
}

// ---------------- agg H=1 (2 nodes/wave) + fused classifier + log_softmax ----
__global__ __launch_bounds__(256) void gat_agg_h1_cls(
    const _Float16* __restrict__ hhf, const float* __restrict__ als,
    const float* __restrict__ ald, const int* __restrict__ csrsrc,
    const int* __restrict__ offv, const float* __restrict__ bias,
    const float* __restrict__ cW1, const float* __restrict__ cb1,
    const float* __restrict__ cW2, const float* __restrict__ cb2,
    float* __restrict__ outp, int N) {
    __shared__ float w1s[2048];   // cW1 [64][32]
    __shared__ float w2s[64];     // cW2 [32][2]
    __shared__ float b1s[32];
    __shared__ int sidAll[4][2][36];
    __shared__ float wAll[4][2][36];
    __shared__ float xsAll[4][2][64];
    for (int i = threadIdx.x; i < 2048; i += 256) w1s[i] = cW1[i];
    if (threadIdx.x < 64) w2s[threadIdx.x] = cW2[threadIdx.x];
    if (threadIdx.x < 32) b1s[threadIdx.x] = cb1[threadIdx.x];
    __syncthreads();   // uniform, once
    const int wv = threadIdx.x >> 6;
    const int l = threadIdx.x & 63;
    const int half = l >> 5;
    const int q = l & 31;
    const int n = (blockIdx.x * 4 + wv) * 2 + half;
    if (n >= N) return;
    int* sid = sidAll[wv][half];
    float* wsh = wAll[wv][half];
    float* xs = xsAll[wv][half];
    const int start = offv[n];
    const int deg = offv[n + 1] - start;
    const float ad = ald[n];
    const float wself = fexp2(LRELU(als[n] + ad));
    float acc0, acc1;
    {
        const f16x2 hv = *(const f16x2*)(hhf + (size_t)n * 64 + q * 2);
        acc0 = (float)hv[0] * wself;
        acc1 = (float)hv[1] * wself;
    }
    float dsum = wself;

    for (int base = 0; base < deg; base += 32) {
        const int nb = min(32, deg - base);
        int s = 0;
        float w = 0.f;
        if (q < nb) {
            s = csrsrc[start + base + q];
            w = fexp2(LRELU(als[s] + ad));
        }
        sid[q] = s;
        wsh[q] = w;
        __threadfence_block();
        for (int i = 0; i < nb; ++i) {
            const int si = sid[i];
            const float wi = wsh[i];
            const f16x2 hv = *(const f16x2*)(hhf + (size_t)si * 64 + q * 2);
            dsum += wi;
            acc0 += (float)hv[0] * wi;
            acc1 += (float)hv[1] * wi;
        }
        __threadfence_block();
    }
    const float inv = 1.f / (dsum + 1e-16f);
    const float v0 = fmaxf(acc0 * inv + bias[q * 2], 0.f);
    const float v1 = fmaxf(acc1 * inv + bias[q * 2 + 1], 0.f);
    // ---- classifier (wave-half parallel: 32 lanes = 32 hidden units) ----
    xs[q * 2] = v0;
    xs[q * 2 + 1] = v1;
    __threadfence_block();
    float s1 = b1s[q];
#pragma unroll 8
    for (int c = 0; c < 64; ++c) s1 += xs[c] * w1s[c * 32 + q];
    const float hid = fmaxf(s1, 0.f);
    float c0 = hid * w2s[q * 2];
    float c1 = hid * w2s[q * 2 + 1];
#pragma unroll
    for (int o = 16; o; o >>= 1) {   // reduce within 32-lane half
        c0 += __shfl_xor(c0, o);
        c1 += __shfl_xor(c1, o);
    }
    const float l0 = c0 + cb2[0];
    const float l1 = c1 + cb2[1];
    const float mm = fmaxf(l0, l1);
    const float lse = mm + logf(__expf(l0 - mm) + __expf(l1 - mm));
    if (q == 0) {
        outp[(size_t)n * 2 + 0] = l0 - lse;
        outp[(size_t)n * 2 + 1] = l1 - lse;
    }
}

extern "C" void kernel_launch(void* const* d_in, const int* in_sizes, int n_in,
                              void* d_out, int out_size, void* d_ws, size_t ws_size,
                              hipStream_t stream) {
    const float* x   = (const float*)d_in[0];
    const int*   ei  = (const int*)d_in[1];
    const float* W1  = (const float*)d_in[2];
    const float* a1s = (const float*)d_in[3];
    const float* a1d = (const float*)d_in[4];
    const float* b1  = (const float*)d_in[5];
    const float* W2  = (const float*)d_in[6];
    const float* a2s = (const float*)d_in[7];
    const float* a2d = (const float*)d_in[8];
    const float* b2  = (const float*)d_in[9];
    const float* W3  = (const float*)d_in[10];
    const float* a3s = (const float*)d_in[11];
    const float* a3d = (const float*)d_in[12];
    const float* b3  = (const float*)d_in[13];
    const float* cW1 = (const float*)d_in[14];
    const float* cb1 = (const float*)d_in[15];
    const float* cW2 = (const float*)d_in[16];
    const float* cb2 = (const float*)d_in[17];

    const int N = in_sizes[0] / 128;   // 50000
    const int E = in_sizes[1] / 2;     // 500000
    const int* srcv = ei;
    const int* dstv = ei + E;

    // workspace layout, all segments 16B-aligned
    char* p = (char*)d_ws;
    _Float16* slotA = (_Float16*)p; p += (size_t)N * 256 * 2;   // h1h / h2h / h3h
    _Float16* slotB = (_Float16*)p; p += (size_t)N * 256 * 2;   // a1h / a2h
    float* als = (float*)p; p += (size_t)N * 4 * 4;
    float* ald = (float*)p; p += (size_t)N * 4 * 4;
    int* cnt = (int*)p; p += (size_t)N * 4;
    int* offv = (int*)p; p += (size_t)(N + 4) * 4;
    int* csr = (int*)p; p += (size_t)E * 4;
    _Float16* Wt1 = (_Float16*)p; p += (size_t)128 * 256 * 2;
    _Float16* Wt2 = (_Float16*)p; p += (size_t)256 * 256 * 2;
    _Float16* Wt3 = (_Float16*)p; p += (size_t)256 * 64 * 2;
    int* bsum = (int*)p;

    // weight transposes (one dispatch)
    prep_w_all<<<(128 * 256 + 256 * 256 + 256 * 64 + 255) / 256, 256, 0, stream>>>(
        W1, W2, W3, Wt1, Wt2, Wt3);

    // CSR by destination (fill consumes cnt — one memset, 5 dispatches total)
    const int NB = (N + 1023) / 1024;   // 49
    hipMemsetAsync(cnt, 0, (size_t)N * sizeof(int), stream);
    hist_kernel<<<(E + 255) / 256, 256, 0, stream>>>(dstv, cnt, E);
    scan_blk<<<NB, 256, 0, stream>>>(cnt, offv, bsum, N);
    scan_add2<<<NB, 256, 0, stream>>>(offv, bsum, NB, N);
    fill_kernel<<<(E + 255) / 256, 256, 0, stream>>>(dstv, srcv, offv, cnt, csr, E);

    const int MB64 = (N + 63) / 64;      // 782
    const int AGG8 = (N + 7) / 8;        // 6250

    // ---- layer 1 (128 -> 256, H=4, ELU); A = x fp32, converted in staging ----
    gemm64_fused<128, true><<<MB64, 256, 0, stream>>>(
        x, Wt1, a1s, a1d, slotA, als, ald, N);
    gat_agg_h4<<<AGG8, 256, 0, stream>>>(slotA, (const float4*)als,
                                         (const float4*)ald, csr, offv, b1,
                                         slotB, N);

    // ---- layer 2 (256 -> 256, H=4, ELU) ----
    gemm64_fused<256, false><<<MB64, 256, 0, stream>>>(
        slotB, Wt2, a2s, a2d, slotA, als, ald, N);
    gat_agg_h4<<<AGG8, 256, 0, stream>>>(slotA, (const float4*)als,
                                         (const float4*)ald, csr, offv, b2,
                                         slotB, N);

    // ---- layer 3 (256 -> 64, H=1) + agg + classifier + log_softmax ----
    gemm64n64_fused<256><<<MB64, 256, 0, stream>>>(
        slotB, Wt3, a3s, a3d, slotA, als, ald, N);
    gat_agg_h1_cls<<<AGG8, 256, 0, stream>>>(slotA, als, ald, csr, offv, b3,
                                             cW1, cb1, cW2, cb2,
                                             (float*)d_out, N);
}

// Round 15
// 255.441 us; speedup vs baseline: 1.0808x; 1.0087x over previous
//
#include <hip/hip_runtime.h>
#include <hip/hip_fp16.h>

#define LRELU(v) ((v) > 0.f ? (v) : 0.2f * (v))
#define LOG2E 1.44269504088896340736f

typedef _Float16 f16x8 __attribute__((ext_vector_type(8)));
typedef _Float16 f16x2 __attribute__((ext_vector_type(2)));
typedef float f32x4 __attribute__((ext_vector_type(4)));

__device__ __forceinline__ float fexp2(float x) {
    return __builtin_amdgcn_exp2f(x);
}

// ---------------- CSR construction ----------------
__global__ __launch_bounds__(256) void hist_kernel(const int* __restrict__ dst,
                                                   int* __restrict__ cnt, int E) {
    int e = blockIdx.x * 256 + threadIdx.x;
    if (e < E) atomicAdd(&cnt[dst[e]], 1);
}

__global__ __launch_bounds__(256) void scan_blk(const int* __restrict__ cnt,
                                                int* __restrict__ offv,
                                                int* __restrict__ bsum, int N) {
    __shared__ int sh[256];
    const int t = threadIdx.x;
    const int base = blockIdx.x * 1024 + t * 4;
    int v0 = (base + 0 < N) ? cnt[base + 0] : 0;
    int v1 = (base + 1 < N) ? cnt[base + 1] : 0;
    int v2 = (base + 2 < N) ? cnt[base + 2] : 0;
    int v3 = (base + 3 < N) ? cnt[base + 3] : 0;
    const int T = v0 + v1 + v2 + v3;
    sh[t] = T;
    __syncthreads();
    for (int o = 1; o < 256; o <<= 1) {
        int x = (t >= o) ? sh[t - o] : 0;
        __syncthreads();
        sh[t] += x;
        __syncthreads();
    }
    const int excl = sh[t] - T;
    if (t == 255) bsum[blockIdx.x] = sh[255];
    if (base + 0 < N) offv[base + 0] = excl;
    if (base + 1 < N) offv[base + 1] = excl + v0;
    if (base + 2 < N) offv[base + 2] = excl + v0 + v1;
    if (base + 3 < N) offv[base + 3] = excl + v0 + v1 + v2;
}

// scan_add with integrated top-level scan (NB <= 64).
__global__ __launch_bounds__(256) void scan_add2(int* __restrict__ offv,
                                                 const int* __restrict__ bsum,
                                                 int NB, int N) {
    __shared__ int s_add;
    const int t = threadIdx.x;
    const int b = blockIdx.x;
    if (t < 64) {
        int v = (t < NB) ? bsum[t] : 0;
        int pre = (t < b) ? v : 0;
        int tot = v;
#pragma unroll
        for (int o = 32; o; o >>= 1) {
            pre += __shfl_xor(pre, o);
            tot += __shfl_xor(tot, o);
        }
        if (t == 0) {
            s_add = pre;
            if (b == NB - 1) offv[N] = tot;
        }
    }
    __syncthreads();
    const int add = s_add;
    const int base = b * 1024 + t * 4;
#pragma unroll
    for (int i = 0; i < 4; ++i)
        if (base + i < N) offv[base + i] += add;
}

// fill consumes cnt via atomicSub
__global__ __launch_bounds__(256) void fill_kernel(const int* __restrict__ dst,
                                                   const int* __restrict__ srcv,
                                                   const int* __restrict__ offv,
                                                   int* __restrict__ cnt,
                                                   int* __restrict__ csrsrc, int E) {
    int e = blockIdx.x * 256 + threadIdx.x;
    if (e < E) {
        int d = dst[e];
        int p = atomicSub(&cnt[d], 1);
        csrsrc[offv[d] + p - 1] = srcv[e];
    }
}

// ---------------- weight prep (one dispatch) + cnt zeroing fold --------------
__global__ __launch_bounds__(256) void prep_w_all(
    const float* __restrict__ W1, const float* __restrict__ W2,
    const float* __restrict__ W3, _Float16* __restrict__ Wt1,
    _Float16* __restrict__ Wt2, _Float16* __restrict__ Wt3,
    int* __restrict__ cnt, int N) {
    const int S1 = 128 * 256, S2 = 256 * 256, S3 = 256 * 64;
    int idx = blockIdx.x * 256 + threadIdx.x;
    if (idx < N) cnt[idx] = 0;   // folded memset (grid covers N)
    if (idx < S1) {
        int k = idx >> 8, nn = idx & 255;
        Wt1[nn * 128 + k] = (_Float16)W1[idx];
    } else if (idx < S1 + S2) {
        int i = idx - S1;
        int k = i >> 8, nn = i & 255;
        Wt2[nn * 256 + k] = (_Float16)W2[i];
    } else if (idx < S1 + S2 + S3) {
        int i = idx - S1 - S2;
        int k = i >> 6, nn = i & 63;
        Wt3[nn * 256 + k] = (_Float16)W3[i];
    }
}

// ---------------- gemm64: BM=64, N=256, 4 waves (col-split), KC=64 dbuf ------
template <int K, bool AF32>
__global__ __launch_bounds__(256) void gemm64_fused(
    const void* __restrict__ Av, const _Float16* __restrict__ Wt,
    const float* __restrict__ a_s, const float* __restrict__ a_d,
    _Float16* __restrict__ hout, float* __restrict__ als,
    float* __restrict__ ald, int M) {
    constexpr int NKC = K / 64;
    __shared__ f16x8 Atile[2][512];
    const _Float16* A16 = (const _Float16*)Av;
    const float* A32 = (const float*)Av;
    const int t = threadIdx.x;
    const int lane = t & 63;
    const int wn = t >> 6;
    const int m0 = blockIdx.x * 64;
    const int l15 = lane & 15, lg = lane >> 4;

    const int r0 = t >> 3, c0 = t & 7;
    const int r1 = (t + 256) >> 3, c1 = t & 7;
    const int gr0 = min(m0 + r0, M - 1);
    const int gr1 = min(m0 + r1, M - 1);

    f16x8 s0, s1;
    auto FETCH = [&](int kc) {
        if constexpr (AF32) {
            float4 p = *(const float4*)(A32 + (size_t)gr0 * K + kc + c0 * 8);
            float4 q = *(const float4*)(A32 + (size_t)gr0 * K + kc + c0 * 8 + 4);
            s0[0] = (_Float16)p.x; s0[1] = (_Float16)p.y;
            s0[2] = (_Float16)p.z; s0[3] = (_Float16)p.w;
            s0[4] = (_Float16)q.x; s0[5] = (_Float16)q.y;
            s0[6] = (_Float16)q.z; s0[7] = (_Float16)q.w;
            float4 r = *(const float4*)(A32 + (size_t)gr1 * K + kc + c1 * 8);
            float4 u = *(const float4*)(A32 + (size_t)gr1 * K + kc + c1 * 8 + 4);
            s1[0] = (_Float16)r.x; s1[1] = (_Float16)r.y;
            s1[2] = (_Float16)r.z; s1[3] = (_Float16)r.w;
            s1[4] = (_Float16)u.x; s1[5] = (_Float16)u.y;
            s1[6] = (_Float16)u.z; s1[7] = (_Float16)u.w;
        } else {
            s0 = *(const f16x8*)(A16 + (size_t)gr0 * K + kc + c0 * 8);
            s1 = *(const f16x8*)(A16 + (size_t)gr1 * K + kc + c1 * 8);
        }
    };
    FETCH(0);

    f32x4 acc[4][4];
    const f32x4 zz = {0.f, 0.f, 0.f, 0.f};
#pragma unroll
    for (int mi = 0; mi < 4; ++mi)
#pragma unroll
        for (int ni = 0; ni < 4; ++ni) acc[mi][ni] = zz;

    int cur = 0;
#pragma unroll
    for (int kci = 0; kci < NKC; ++kci) {
        Atile[cur][r0 * 8 + (c0 ^ (r0 & 7))] = s0;
        Atile[cur][r1 * 8 + (c1 ^ (r1 & 7))] = s1;
        __syncthreads();
        if (kci + 1 < NKC) FETCH((kci + 1) * 64);
#pragma unroll
        for (int ks = 0; ks < 2; ++ks) {
            f16x8 af[4], bf[4];
#pragma unroll
            for (int mi = 0; mi < 4; ++mi) {
                const int row = mi * 16 + l15;
                af[mi] = Atile[cur][row * 8 + ((ks * 4 + lg) ^ (row & 7))];
            }
#pragma unroll
            for (int ni = 0; ni < 4; ++ni) {
                const int col = wn * 64 + ni * 16 + l15;
                bf[ni] = *(const f16x8*)(Wt + (size_t)col * K + kci * 64 + ks * 32 + lg * 8);
            }
#pragma unroll
            for (int mi = 0; mi < 4; ++mi)
#pragma unroll
                for (int ni = 0; ni < 4; ++ni)
                    acc[mi][ni] = __builtin_amdgcn_mfma_f32_16x16x32_f16(
                        af[mi], bf[ni], acc[mi][ni], 0, 0, 0);
        }
        cur ^= 1;
    }
    const int head = wn;
    float a4s[4], a4d[4];
#pragma unroll
    for (int ni = 0; ni < 4; ++ni) {
        a4s[ni] = a_s[head * 64 + ni * 16 + l15] * LOG2E;
        a4d[ni] = a_d[head * 64 + ni * 16 + l15] * LOG2E;
    }
#pragma unroll
    for (int mi = 0; mi < 4; ++mi)
#pragma unroll
        for (int j = 0; j < 4; ++j) {
            const int r = m0 + mi * 16 + lg * 4 + j;
            if (r < M) {
                float s1v = 0.f, s2v = 0.f;
#pragma unroll
                for (int ni = 0; ni < 4; ++ni) {
                    const float v = acc[mi][ni][j];
                    s1v += v * a4s[ni];
                    s2v += v * a4d[ni];
                    hout[(size_t)r * 256 + wn * 64 + ni * 16 + l15] = (_Float16)v;
                }
#pragma unroll
                for (int o = 8; o; o >>= 1) {
                    s1v += __shfl_xor(s1v, o);
                    s2v += __shfl_xor(s2v, o);
                }
                if (l15 == 0) {
                    als[(size_t)r * 4 + head] = s1v;
                    ald[(size_t)r * 4 + head] = s2v;
                }
            }
        }
}

// ---------------- gemm64n64: BM=64, N=64, 4 waves (row-split), KC=64 dbuf ----
template <int K>
__global__ __launch_bounds__(256) void gemm64n64_fused(
    const _Float16* __restrict__ A16, const _Float16* __restrict__ Wt,
    const float* __restrict__ a_s, const float* __restrict__ a_d,
    _Float16* __restrict__ hout, float* __restrict__ als,
    float* __restrict__ ald, int M) {
    constexpr int NKC = K / 64;
    __shared__ f16x8 Atile[2][512];
    const int t = threadIdx.x;
    const int lane = t & 63;
    const int wv = t >> 6;
    const int m0 = blockIdx.x * 64;
    const int l15 = lane & 15, lg = lane >> 4;

    const int r0 = t >> 3, c0 = t & 7;
    const int r1 = (t + 256) >> 3, c1 = t & 7;
    const int gr0 = min(m0 + r0, M - 1);
    const int gr1 = min(m0 + r1, M - 1);

    f16x8 s0, s1;
    auto FETCH = [&](int kc) {
        s0 = *(const f16x8*)(A16 + (size_t)gr0 * K + kc + c0 * 8);
        s1 = *(const f16x8*)(A16 + (size_t)gr1 * K + kc + c1 * 8);
    };
    FETCH(0);

    f32x4 acc[4];
    const f32x4 zz = {0.f, 0.f, 0.f, 0.f};
#pragma unroll
    for (int ni = 0; ni < 4; ++ni) acc[ni] = zz;

    int cur = 0;
#pragma unroll
    for (int kci = 0; kci < NKC; ++kci) {
        Atile[cur][r0 * 8 + (c0 ^ (r0 & 7))] = s0;
        Atile[cur][r1 * 8 + (c1 ^ (r1 & 7))] = s1;
        __syncthreads();
        if (kci + 1 < NKC) FETCH((kci + 1) * 64);
#pragma unroll
        for (int ks = 0; ks < 2; ++ks) {
            const int row = wv * 16 + l15;
            const f16x8 af = Atile[cur][row * 8 + ((ks * 4 + lg) ^ (row & 7))];
            f16x8 bf[4];
#pragma unroll
            for (int ni = 0; ni < 4; ++ni) {
                const int col = ni * 16 + l15;
                bf[ni] = *(const f16x8*)(Wt + (size_t)col * K + kci * 64 + ks * 32 + lg * 8);
            }
#pragma unroll
            for (int ni = 0; ni < 4; ++ni)
                acc[ni] = __builtin_amdgcn_mfma_f32_16x16x32_f16(
                    af, bf[ni], acc[ni], 0, 0, 0);
        }
        cur ^= 1;
    }
    float a4s[4], a4d[4];
#pragma unroll
    for (int ni = 0; ni < 4; ++ni) {
        a4s[ni] = a_s[ni * 16 + l15] * LOG2E;
        a4d[ni] = a_d[ni * 16 + l15] * LOG2E;
    }
#pragma unroll
    for (int j = 0; j < 4; ++j) {
        const int r = m0 + wv * 16 + lg * 4 + j;
        if (r < M) {
            float s1v = 0.f, s2v = 0.f;
#pragma unroll
            for (int ni = 0; ni < 4; ++ni) {
                const float v = acc[ni][j];
                s1v += v * a4s[ni];
                s2v += v * a4d[ni];
                hout[(size_t)r * 64 + ni * 16 + l15] = (_Float16)v;
            }
#pragma unroll
            for (int o = 8; o; o >>= 1) {
                s1v += __shfl_xor(s1v, o);
                s2v += __shfl_xor(s2v, o);
            }
            if (l15 == 0) {
                als[r] = s1v;
                ald[r] = s2v;
            }
        }
    }
}

// ---------------- aggregation H=4: 2 nodes per wave (at gather plateau) -------
__global__ __launch_bounds__(256) void gat_agg_h4(
    const _Float16* __restrict__ hhf, const float4* __restrict__ als4,
    const float4* __restrict__ ald4, const int* __restrict__ csrsrc,
    const int* __restrict__ offv, const float* __restrict__ bias,
    _Float16* __restrict__ outh, int N) {
    __shared__ int sidAll[4][2][36];
    __shared__ float wTAll[4][2][4][36];
    const int wv = threadIdx.x >> 6;
    const int l = threadIdx.x & 63;
    const int half = l >> 5;
    const int q = l & 31;
    const int n = (blockIdx.x * 4 + wv) * 2 + half;
    if (n >= N) return;
    const int hh = q >> 3;
    int* sid = sidAll[wv][half];
    float* wrow = wTAll[wv][half][hh];
    float (*wT)[36] = wTAll[wv][half];
    const int start = offv[n];
    const int deg = offv[n + 1] - start;
    const float4 ad = ald4[n];
    const float4 asf = als4[n];
    float4 ws4;
    ws4.x = fexp2(LRELU(asf.x + ad.x));
    ws4.y = fexp2(LRELU(asf.y + ad.y));
    ws4.z = fexp2(LRELU(asf.z + ad.z));
    ws4.w = fexp2(LRELU(asf.w + ad.w));
    float wself = ws4.x;
    wself = (hh == 1) ? ws4.y : wself;
    wself = (hh == 2) ? ws4.z : wself;
    wself = (hh == 3) ? ws4.w : wself;
    float accA[8], accB[8] = {};
    {
        const f16x8 hv = *(const f16x8*)(hhf + (size_t)n * 256 + q * 8);
#pragma unroll
        for (int c = 0; c < 8; ++c) accA[c] = (float)hv[c] * wself;
    }
    float dsum = wself;

    for (int base = 0; base < deg; base += 32) {
        const int nb = min(32, deg - base);
        int s = 0;
        float4 w4 = {0.f, 0.f, 0.f, 0.f};
        if (q < nb) {
            s = csrsrc[start + base + q];
            const float4 av = als4[s];
            w4.x = fexp2(LRELU(av.x + ad.x));
            w4.y = fexp2(LRELU(av.y + ad.y));
            w4.z = fexp2(LRELU(av.z + ad.z));
            w4.w = fexp2(LRELU(av.w + ad.w));
        }
        sid[q] = s;
        wT[0][q] = w4.x;
        wT[1][q] = w4.y;
        wT[2][q] = w4.z;
        wT[3][q] = w4.w;
        __threadfence_block();
        int i = 0;
        for (; i + 1 < nb; i += 2) {
            const int sA = sid[i], sB = sid[i + 1];
            const float wA = wrow[i], wB = wrow[i + 1];
            const f16x8 hA = *(const f16x8*)(hhf + (size_t)sA * 256 + q * 8);
            const f16x8 hB = *(const f16x8*)(hhf + (size_t)sB * 256 + q * 8);
            dsum += wA + wB;
#pragma unroll
            for (int c = 0; c < 8; ++c) {
                accA[c] += (float)hA[c] * wA;
                accB[c] += (float)hB[c] * wB;
            }
        }
        if (i < nb) {
            const int sA = sid[i];
            const float wA = wrow[i];
            const f16x8 hA = *(const f16x8*)(hhf + (size_t)sA * 256 + q * 8);
            dsum += wA;
#pragma unroll
            for (int c = 0; c < 8; ++c) accA[c] += (float)hA[c] * wA;
        }
        __threadfence_block();
    }
    const float inv = 1.f / (dsum + 1e-16f);
    const float4 bv0 = *(const float4*)(bias + q * 8);
    const float4 bv1 = *(const float4*)(bias + q * 8 + 4);
    float o8[8];
#pragma unroll
    for (int c = 0; c < 8; ++c) o8[c] = (accA[c] + accB[c]) * inv;
    o8[0] += bv0.x; o8[1] += bv0.y; o8[2] += bv0.z; o8[3] += bv0.w;
    o8[4] += bv1.x; o8[5] += bv1.y; o8[6] += bv1.z; o8[7] += bv1.w;
#pragma unroll
    for (int c = 0; c < 8; ++c)
        o8[c] = (o8[c] > 0.f) ? o8[c] : (__expf(o8[c]) - 1.f);
    f16x8 st;
#pragma unroll
    for (int c = 0; c < 8; ++c) st[c] = (_Float16)o8[c];
    *(f16x8*)(outh + (size_t)n * 256 + q * 8) = st;
}

// ---------------- agg H=1 (2 nodes/wave) + fused classifier + log_softmax ----
__global__ __launch_bounds__(256) void gat_agg_h1_cls(
    const _Float16* __restrict__ hhf, const float* __restrict__ als,
    const float* __restrict__ ald, const int* __restrict__ csrsrc,
    const int* __restrict__ offv, const float* __restrict__ bias,
    const float* __restrict__ cW1, const float* __restrict__ cb1,
    const float* __restrict__ cW2, const float* __restrict__ cb2,
    float* __restrict__ outp, int N) {
    __shared__ float w1s[2048];
    __shared__ float w2s[64];
    __shared__ float b1s[32];
    __shared__ int sidAll[4][2][36];
    __shared__ float wAll[4][2][36];
    __shared__ float xsAll[4][2][64];
    for (int i = threadIdx.x; i < 2048; i += 256) w1s[i] = cW1[i];
    if (threadIdx.x < 64) w2s[threadIdx.x] = cW2[threadIdx.x];
    if (threadIdx.x < 32) b1s[threadIdx.x] = cb1[threadIdx.x];
    __syncthreads();
    const int wv = threadIdx.x >> 6;
    const int l = threadIdx.x & 63;
    const int half = l >> 5;
    const int q = l & 31;
    const int n = (blockIdx.x * 4 + wv) * 2 + half;
    if (n >= N) return;
    int* sid = sidAll[wv][half];
    float* wsh = wAll[wv][half];
    float* xs = xsAll[wv][half];
    const int start = offv[n];
    const int deg = offv[n + 1] - start;
    const float ad = ald[n];
    const float wself = fexp2(LRELU(als[n] + ad));
    float acc0, acc1;
    {
        const f16x2 hv = *(const f16x2*)(hhf + (size_t)n * 64 + q * 2);
        acc0 = (float)hv[0] * wself;
        acc1 = (float)hv[1] * wself;
    }
    float dsum = wself;

    for (int base = 0; base < deg; base += 32) {
        const int nb = min(32, deg - base);
        int s = 0;
        float w = 0.f;
        if (q < nb) {
            s = csrsrc[start + base + q];
            w = fexp2(LRELU(als[s] + ad));
        }
        sid[q] = s;
        wsh[q] = w;
        __threadfence_block();
        for (int i = 0; i < nb; ++i) {
            const int si = sid[i];
            const float wi = wsh[i];
            const f16x2 hv = *(const f16x2*)(hhf + (size_t)si * 64 + q * 2);
            dsum += wi;
            acc0 += (float)hv[0] * wi;
            acc1 += (float)hv[1] * wi;
        }
        __threadfence_block();
    }
    const float inv = 1.f / (dsum + 1e-16f);
    const float v0 = fmaxf(acc0 * inv + bias[q * 2], 0.f);
    const float v1 = fmaxf(acc1 * inv + bias[q * 2 + 1], 0.f);
    xs[q * 2] = v0;
    xs[q * 2 + 1] = v1;
    __threadfence_block();
    float s1 = b1s[q];
#pragma unroll 8
    for (int c = 0; c < 64; ++c) s1 += xs[c] * w1s[c * 32 + q];
    const float hid = fmaxf(s1, 0.f);
    float c0 = hid * w2s[q * 2];
    float c1 = hid * w2s[q * 2 + 1];
#pragma unroll
    for (int o = 16; o; o >>= 1) {
        c0 += __shfl_xor(c0, o);
        c1 += __shfl_xor(c1, o);
    }
    const float l0 = c0 + cb2[0];
    const float l1 = c1 + cb2[1];
    const float mm = fmaxf(l0, l1);
    const float lse = mm + logf(__expf(l0 - mm) + __expf(l1 - mm));
    if (q == 0) {
        outp[(size_t)n * 2 + 0] = l0 - lse;
        outp[(size_t)n * 2 + 1] = l1 - lse;
    }
}

extern "C" void kernel_launch(void* const* d_in, const int* in_sizes, int n_in,
                              void* d_out, int out_size, void* d_ws, size_t ws_size,
                              hipStream_t stream) {
    const float* x   = (const float*)d_in[0];
    const int*   ei  = (const int*)d_in[1];
    const float* W1  = (const float*)d_in[2];
    const float* a1s = (const float*)d_in[3];
    const float* a1d = (const float*)d_in[4];
    const float* b1  = (const float*)d_in[5];
    const float* W2  = (const float*)d_in[6];
    const float* a2s = (const float*)d_in[7];
    const float* a2d = (const float*)d_in[8];
    const float* b2  = (const float*)d_in[9];
    const float* W3  = (const float*)d_in[10];
    const float* a3s = (const float*)d_in[11];
    const float* a3d = (const float*)d_in[12];
    const float* b3  = (const float*)d_in[13];
    const float* cW1 = (const float*)d_in[14];
    const float* cb1 = (const float*)d_in[15];
    const float* cW2 = (const float*)d_in[16];
    const float* cb2 = (const float*)d_in[17];

    const int N = in_sizes[0] / 128;   // 50000
    const int E = in_sizes[1] / 2;     // 500000
    const int* srcv = ei;
    const int* dstv = ei + E;

    // workspace layout, all segments 16B-aligned
    char* p = (char*)d_ws;
    _Float16* slotA = (_Float16*)p; p += (size_t)N * 256 * 2;   // h1h / h2h / h3h
    _Float16* slotB = (_Float16*)p; p += (size_t)N * 256 * 2;   // a1h / a2h
    float* als = (float*)p; p += (size_t)N * 4 * 4;
    float* ald = (float*)p; p += (size_t)N * 4 * 4;
    int* cnt = (int*)p; p += (size_t)N * 4;
    int* offv = (int*)p; p += (size_t)(N + 4) * 4;
    int* csr = (int*)p; p += (size_t)E * 4;
    _Float16* Wt1 = (_Float16*)p; p += (size_t)128 * 256 * 2;
    _Float16* Wt2 = (_Float16*)p; p += (size_t)256 * 256 * 2;
    _Float16* Wt3 = (_Float16*)p; p += (size_t)256 * 64 * 2;
    int* bsum = (int*)p;

    // weight transposes + cnt zeroing (one dispatch; grid covers N)
    prep_w_all<<<(128 * 256 + 256 * 256 + 256 * 64 + 255) / 256, 256, 0, stream>>>(
        W1, W2, W3, Wt1, Wt2, Wt3, cnt, N);

    // CSR by destination (4 dispatches)
    const int NB = (N + 1023) / 1024;   // 49
    hist_kernel<<<(E + 255) / 256, 256, 0, stream>>>(dstv, cnt, E);
    scan_blk<<<NB, 256, 0, stream>>>(cnt, offv, bsum, N);
    scan_add2<<<NB, 256, 0, stream>>>(offv, bsum, NB, N);
    fill_kernel<<<(E + 255) / 256, 256, 0, stream>>>(dstv, srcv, offv, cnt, csr, E);

    const int MB64 = (N + 63) / 64;      // 782
    const int AGG8 = (N + 7) / 8;        // 6250

    // ---- layer 1 (128 -> 256, H=4, ELU); A = x fp32, converted in staging ----
    gemm64_fused<128, true><<<MB64, 256, 0, stream>>>(
        x, Wt1, a1s, a1d, slotA, als, ald, N);
    gat_agg_h4<<<AGG8, 256, 0, stream>>>(slotA, (const float4*)als,
                                         (const float4*)ald, csr, offv, b1,
                                         slotB, N);

    // ---- layer 2 (256 -> 256, H=4, ELU) ----
    gemm64_fused<256, false><<<MB64, 256, 0, stream>>>(
        slotB, Wt2, a2s, a2d, slotA, als, ald, N);
    gat_agg_h4<<<AGG8, 256, 0, stream>>>(slotA, (const float4*)als,
                                         (const float4*)ald, csr, offv, b2,
                                         slotB, N);

    // ---- layer 3 (256 -> 64, H=1) + agg + classifier + log_softmax ----
    gemm64n64_fused<256><<<MB64, 256, 0, stream>>>(
        slotB, Wt3, a3s, a3d, slotA, als, ald, N);
    gat_agg_h1_cls<<<AGG8, 256, 0, stream>>>(slotA, als, ald, csr, offv, b3,
                                             cW1, cb1, cW2, cb2,
                                             (float*)d_out, N);
}